// Round 3
// baseline (405.422 us; speedup 1.0000x reference)
//
#include <hip/hip_runtime.h>
#include <hip/hip_bf16.h>

#define NN 50000
#define EE 800000
#define GG 64
#define NBUCK 196              // ceil(NN/256)
#define ABLOCKS 125            // edge chunks: 125 x 6400 = 800000
#define CHUNK 6400
#define BCAP 8192              // LDS bucket capacity (mean 4096, sd ~64)
#define SPANCAP 512            // per-block (16-row) staged CSR index cap; mean 256, sd 16
#define PARTN 3125             // conv grid blocks (NN/16)

typedef __attribute__((ext_vector_type(8))) short bf16x8;
typedef __attribute__((ext_vector_type(4))) float f32x4;

// ---- bf16 helpers ----
__device__ __forceinline__ float bflo(unsigned u) { return __uint_as_float(u << 16); }
__device__ __forceinline__ float bfhi(unsigned u) { return __uint_as_float(u & 0xffff0000u); }
__device__ __forceinline__ float b2f(unsigned short s) { return __uint_as_float(((unsigned)s) << 16); }
__device__ __forceinline__ unsigned short f2bf(float f) {
    __hip_bfloat16 h = __float2bfloat16(f);
    union { __hip_bfloat16 h; unsigned short u; } cv; cv.h = h; return cv.u;
}

// -------------------------------------------------------------------------
// Detector (verified r2-r9): flags[0]=fp32? flags[1]=int64?
// -------------------------------------------------------------------------
__global__ void detect_kernel(const unsigned* __restrict__ xw,
                              const unsigned* __restrict__ eiw,
                              int* __restrict__ flags) {
    __shared__ int s_cnt, s_nz;
    if (threadIdx.x == 0) { s_cnt = 0; s_nz = 0; }
    __syncthreads();
    int cnt = 0;
    for (int i = threadIdx.x; i < 4096; i += 256) {
        unsigned w = xw[(size_t)i * 711];
        unsigned elo = (w >> 7) & 0xFF;
        if (elo >= 100 && elo <= 140) cnt++;
    }
    int nz = 0;
    for (int i = threadIdx.x; i < 1024; i += 256) {
        unsigned w = eiw[(size_t)i * 1560 + 1];
        if (w != 0) nz++;
    }
    atomicAdd(&s_cnt, cnt);
    atomicAdd(&s_nz, nz);
    __syncthreads();
    if (threadIdx.x == 0) {
        flags[0] = (s_cnt < 3600) ? 1 : 0;
        flags[1] = (s_nz  < 8)    ? 1 : 0;
    }
}

// -------------------------------------------------------------------------
// Mega prep: [0,3125) convert x; [3125,3674) convert weights;
// [3674,3799) bucket_count; [3799,4055) zero pool slices (1 MiB).
// -------------------------------------------------------------------------
struct WPtrs { const void* p[15]; };

__global__ __launch_bounds__(256) void prep_kernel(const void* __restrict__ xsrc,
                                                   const unsigned* __restrict__ eiw,
                                                   WPtrs wp,
                                                   unsigned short* __restrict__ arena,
                                                   int* __restrict__ counts,
                                                   uint4* __restrict__ zero_region,
                                                   const int* __restrict__ flags) {
    const int b = blockIdx.x;
    const int tid = threadIdx.x;
    const int isF32 = flags[0];

    if (b < 3125) {
        const int total4 = NN * 128 / 4;   // 1,600,000
        for (int i = b * 256 + tid; i < total4; i += 800000) {
            uint2 o;
            if (isF32) {
                float4 f = ((const float4*)xsrc)[i];
                o.x = (unsigned)f2bf(f.x) | ((unsigned)f2bf(f.y) << 16);
                o.y = (unsigned)f2bf(f.z) | ((unsigned)f2bf(f.w) << 16);
            } else {
                o = ((const uint2*)xsrc)[i];
            }
            ((uint2*)arena)[i] = o;
        }
    } else if (b < 3674) {
        const int cnt[15] = {16384,128,16384, 16384,128,16384, 16384,128,16384,
                             32768,128,8192,64,640,10};
        const int dst[15] = {19200000,19232768,19216384, 19232896,19265664,19249280,
                             19265792,19298560,19282176,
                             19298688,19331456,19331584,19339776,19339840,19340480};
        const int total = 140490;
        int i = (b - 3125) * 256 + tid;
        if (i < total) {
            int seg = 0, base = 0;
            while (i - base >= cnt[seg]) { base += cnt[seg]; ++seg; }
            int off = i - base;
            const void* s = wp.p[seg];
            arena[dst[seg] + off] =
                isF32 ? f2bf(((const float*)s)[off]) : ((const unsigned short*)s)[off];
        }
    } else if (b < 3799) {
        __shared__ int hist[256];
        hist[tid] = 0;
        __syncthreads();
        const int i64 = flags[1];
        const int e0 = (b - 3674) * CHUNK;
        for (int it = 0; it < CHUNK / 256; ++it) {
            int e = e0 + it * 256 + tid;
            int d = (int)(i64 ? eiw[(size_t)2 * (EE + e)] : eiw[EE + e]);
            atomicAdd(&hist[d >> 8], 1);
        }
        __syncthreads();
        counts[(b - 3674) * 256 + tid] = hist[tid];
    } else {
        // zero pool accumulators: 256 blocks x 256 thr x 16 B = 1,048,576 B
        zero_region[(b - 3799) * 256 + tid] = (uint4){0, 0, 0, 0};
    }
}

// -------------------------------------------------------------------------
// CSR build via 2-level bucket sort (verified r6-r9).
// bucket_offsets additionally computes gstart[65] (lower_bound of each graph
// in the sorted batch array) in its otherwise-idle single block.
// -------------------------------------------------------------------------
__global__ __launch_bounds__(256) void bucket_offsets(const int* __restrict__ counts,
                                                      int* __restrict__ offsets,
                                                      int* __restrict__ bucket_base,
                                                      const unsigned* __restrict__ bw,
                                                      int* __restrict__ gstart,
                                                      const int* __restrict__ flags) {
    __shared__ int s[256];
    const int t = threadIdx.x;
    int col = 0;
    for (int b = 0; b < ABLOCKS; ++b) col += counts[b * 256 + t];
    s[t] = col;
    __syncthreads();
    for (int d = 1; d < 256; d <<= 1) {
        int x = (t >= d) ? s[t - d] : 0;
        __syncthreads();
        s[t] += x;
        __syncthreads();
    }
    int base = s[t] - col;
    bucket_base[t] = base;
    if (t == 255) bucket_base[256] = s[255];
    int run = base;
    for (int b = 0; b < ABLOCKS; ++b) {
        offsets[b * 256 + t] = run;
        run += counts[b * 256 + t];
    }
    // ---- gstart: lower_bound(batch, g) for g in [0,64]; gstart[64]=NN ----
    if (t < 65) gstart[t] = NN;
    __syncthreads();
    const int i64 = flags[1];
    for (int i = t; i < NN; i += 256) {
        int g  = (int)(i64 ? bw[(size_t)2 * i] : bw[i]);
        int gp = (i == 0) ? -1 : (int)(i64 ? bw[(size_t)2 * (i - 1)] : bw[i - 1]);
        for (int gg = gp + 1; gg <= g; ++gg) gstart[gg] = i;   // unique writer per gg
    }
}

__global__ __launch_bounds__(256) void bucket_scatter(const unsigned* __restrict__ eiw,
                                                      const int* __restrict__ offsets,
                                                      unsigned* __restrict__ packed,
                                                      const int* __restrict__ flags) {
    __shared__ int cur[256];
    cur[threadIdx.x] = offsets[blockIdx.x * 256 + threadIdx.x];
    __syncthreads();
    int i64 = flags[1];
    int e0 = blockIdx.x * CHUNK;
    for (int it = 0; it < CHUNK / 256; ++it) {
        int e = e0 + it * 256 + threadIdx.x;
        int s = (int)(i64 ? eiw[(size_t)2 * e]        : eiw[e]);
        int d = (int)(i64 ? eiw[(size_t)2 * (EE + e)] : eiw[EE + e]);
        int pos = atomicAdd(&cur[d >> 8], 1);
        packed[pos] = ((unsigned)s << 8) | (unsigned)(d & 255);
    }
}

__global__ __launch_bounds__(256) void bucket_sort(const unsigned* __restrict__ packed,
                                                   const int* __restrict__ bucket_base,
                                                   unsigned short* __restrict__ csr_src,  // u16: src < 65536
                                                   int* __restrict__ row_ptr) {
    __shared__ unsigned sbuf[BCAP];
    __shared__ int hist[256];
    __shared__ int cur[256];
    const int t = threadIdx.x;
    const int b = blockIdx.x;
    const int lo = bucket_base[b];
    int n = bucket_base[b + 1] - lo;
    if (n > BCAP) n = BCAP;

    hist[t] = 0;
    __syncthreads();
    for (int i = t; i < n; i += 256) {
        unsigned p = packed[lo + i];
        sbuf[i] = p;
        atomicAdd(&hist[p & 255], 1);
    }
    __syncthreads();
    int v = hist[t];
    __shared__ int s[256];
    s[t] = v;
    __syncthreads();
    for (int d = 1; d < 256; d <<= 1) {
        int x = (t >= d) ? s[t - d] : 0;
        __syncthreads();
        s[t] += x;
        __syncthreads();
    }
    int start = s[t] - v;
    int node = b * 256 + t;
    if (node < NN) row_ptr[node] = lo + start;
    if (b == 0 && t == 0) row_ptr[NN] = EE;
    cur[t] = start;
    __syncthreads();
    for (int i = t; i < n; i += 256) {
        unsigned p = sbuf[i];
        int pos = atomicAdd(&cur[p & 255], 1);
        csr_src[lo + pos] = (unsigned short)(p >> 8);
    }
}

// -------------------------------------------------------------------------
// Fused conv v6:
//  - gather 16-deep (16 uint4 in flight per wave; was 8) + 8-batch + tail;
//    launch_bounds(256,4) gives VGPR headroom (~110), cap 16 waves/CU.
//  - root-row A-frags hoisted BEFORE phase 1 (latency overlaps gather).
//  - csr indices are u16 (halves index staging traffic).
//  - pool: dense per-block partial {mx,sm} packed bf16 in u32 plane
//    (non-atomic, coalesced) for the block's FIRST graph run; atomics only
//    for boundary-crossing runs (~2% of blocks). ppart==null -> pure atomics.
// -------------------------------------------------------------------------
__global__ __launch_bounds__(256, 4) void conv_fused(const unsigned short* __restrict__ hin,
                                                     const int* __restrict__ row_ptr,
                                                     const unsigned short* __restrict__ csr16,
                                                     const unsigned short* __restrict__ Wrel,
                                                     const unsigned short* __restrict__ Wroot,
                                                     const unsigned short* __restrict__ brel,
                                                     const unsigned* __restrict__ bw,
                                                     unsigned* __restrict__ pmx,   // layer's [8][64][128]
                                                     float* __restrict__ psum,     // [8][64][128] (shared)
                                                     unsigned* __restrict__ ppart, // layer's [3125][128] u32 or null
                                                     unsigned short* __restrict__ outb,
                                                     void* __restrict__ outG,
                                                     const int* __restrict__ flags) {
    __shared__ __align__(16) unsigned short tile[16][136];   // 4.25 KB
    __shared__ int sbatch[16];
    __shared__ int s_rp[17];
    __shared__ unsigned short s_idx[SPANCAP];                // 1 KB

    const int tid  = threadIdx.x;
    const int wv   = tid >> 6;
    const int lane = tid & 63;
    const int m0   = blockIdx.x * 16;
    const int mrow = lane & 15;
    const int quad = lane >> 4;

    // ---- Phase 0: stage row_ptr + CSR indices; sbatch piggybacks ----
    if (tid < 17) s_rp[tid] = row_ptr[m0 + tid];
    if (tid >= 32 && tid < 48) {
        const int i64 = flags[1];
        int rr = m0 + (tid - 32);
        sbatch[tid - 32] = (int)(i64 ? bw[(size_t)2 * rr] : bw[rr]);
    }
    __syncthreads();
    const int base = s_rp[0];
    const int span = s_rp[16] - base;
    const int nst  = (span < SPANCAP) ? span : SPANCAP;
    for (int i = tid; i < nst; i += 256) s_idx[i] = csr16[base + i];

    // ---- root-row A-frag hoist (consumed in phase 2, kk=4..7) ----
    bf16x8 rootv[4];
    #pragma unroll
    for (int k2 = 0; k2 < 4; ++k2)
        rootv[k2] = *(const bf16x8*)(hin + (size_t)(m0 + mrow) * 128 + k2 * 32 + quad * 8);

    __syncthreads();

    // ---- Phase 1: gather, quad-per-row, uint4 per lane, 16-deep ----
    const int qd  = lane >> 4;        // which of the wave's 4 rows
    const int l16 = lane & 15;        // channel block: [l16*8, l16*8+8)
    const int lr  = wv * 4 + qd;
    const int jb  = s_rp[lr]     - base;
    const int je  = s_rp[lr + 1] - base;
    const uint4* h16 = (const uint4*)hin;   // 16 uint4 per 128-ch row

    float a0 = 0.f, a1 = 0.f, a2 = 0.f, a3 = 0.f,
          a4 = 0.f, a5 = 0.f, a6 = 0.f, a7 = 0.f;

    if (span <= SPANCAP) {
        int j = jb;
        for (; j + 16 <= je; j += 16) {      // 16 loads in flight
            int idx[16];
            #pragma unroll
            for (int q = 0; q < 16; ++q) idx[q] = s_idx[j + q];
            uint4 u[16];
            #pragma unroll
            for (int q = 0; q < 16; ++q) u[q] = h16[(size_t)idx[q] * 16 + l16];
            #pragma unroll
            for (int q = 0; q < 16; ++q) {
                a0 += bflo(u[q].x); a1 += bfhi(u[q].x);
                a2 += bflo(u[q].y); a3 += bfhi(u[q].y);
                a4 += bflo(u[q].z); a5 += bfhi(u[q].z);
                a6 += bflo(u[q].w); a7 += bfhi(u[q].w);
            }
        }
        if (j + 8 <= je) {                   // one 8-deep batch
            int idx[8];
            #pragma unroll
            for (int q = 0; q < 8; ++q) idx[q] = s_idx[j + q];
            uint4 u[8];
            #pragma unroll
            for (int q = 0; q < 8; ++q) u[q] = h16[(size_t)idx[q] * 16 + l16];
            #pragma unroll
            for (int q = 0; q < 8; ++q) {
                a0 += bflo(u[q].x); a1 += bfhi(u[q].x);
                a2 += bflo(u[q].y); a3 += bfhi(u[q].y);
                a4 += bflo(u[q].z); a5 += bfhi(u[q].z);
                a6 += bflo(u[q].w); a7 += bfhi(u[q].w);
            }
            j += 8;
        }
        if (j < je) {                        // one predicated tail batch
            #pragma unroll
            for (int q = 0; q < 8; ++q) {
                int ii = j + q;
                int ic = (ii < je - 1) ? ii : (je - 1);
                float sc = (ii < je) ? 1.f : 0.f;
                uint4 u = h16[(size_t)s_idx[ic] * 16 + l16];
                a0 = fmaf(bflo(u.x), sc, a0); a1 = fmaf(bfhi(u.x), sc, a1);
                a2 = fmaf(bflo(u.y), sc, a2); a3 = fmaf(bfhi(u.y), sc, a3);
                a4 = fmaf(bflo(u.z), sc, a4); a5 = fmaf(bfhi(u.z), sc, a5);
                a6 = fmaf(bflo(u.w), sc, a6); a7 = fmaf(bfhi(u.w), sc, a7);
            }
        }
    } else {
        // pathological span (never expected for this input): global indices
        for (int j = jb; j < je; j += 8) {
            #pragma unroll
            for (int q = 0; q < 8; ++q) {
                int ii = j + q;
                int ic = (ii < je - 1) ? ii : (je - 1);
                float sc = (ii < je) ? 1.f : 0.f;
                uint4 u = h16[(size_t)csr16[base + ic] * 16 + l16];
                a0 = fmaf(bflo(u.x), sc, a0); a1 = fmaf(bfhi(u.x), sc, a1);
                a2 = fmaf(bflo(u.y), sc, a2); a3 = fmaf(bfhi(u.y), sc, a3);
                a4 = fmaf(bflo(u.z), sc, a4); a5 = fmaf(bfhi(u.z), sc, a5);
                a6 = fmaf(bflo(u.w), sc, a6); a7 = fmaf(bfhi(u.w), sc, a7);
            }
        }
    }

    {
        uint4 o;
        o.x = (unsigned)f2bf(a0) | ((unsigned)f2bf(a1) << 16);
        o.y = (unsigned)f2bf(a2) | ((unsigned)f2bf(a3) << 16);
        o.z = (unsigned)f2bf(a4) | ((unsigned)f2bf(a5) << 16);
        o.w = (unsigned)f2bf(a6) | ((unsigned)f2bf(a7) << 16);
        *(uint4*)&tile[lr][l16 * 8] = o;
    }
    __syncthreads();

    // ---- Phase 2: MFMA GEMM, wave owns a 32-col slice ----
    f32x4 acc[2];
    acc[0] = (f32x4){0.f, 0.f, 0.f, 0.f};
    acc[1] = (f32x4){0.f, 0.f, 0.f, 0.f};

    #pragma unroll
    for (int kk = 0; kk < 8; ++kk) {
        const unsigned short* Bs = (kk < 4) ? Wrel : Wroot;
        const int kc = (kk & 3) * 32 + quad * 8;
        bf16x8 a;
        if (kk < 4) a = *(const bf16x8*)&tile[mrow][kc];
        else        a = rootv[kk - 4];
        #pragma unroll
        for (int n = 0; n < 2; ++n) {
            const int col0 = (wv * 2 + n) * 16;
            bf16x8 b = *(const bf16x8*)(Bs + (size_t)(col0 + mrow) * 128 + kc);
            acc[n] = __builtin_amdgcn_mfma_f32_16x16x32_bf16(a, b, acc[n], 0, 0, 0);
        }
    }

    __syncthreads();   // RACE FIX: all agg A-frag reads complete before h overwrites tile

    #pragma unroll
    for (int n = 0; n < 2; ++n) {
        const int col = (wv * 2 + n) * 16 + mrow;
        const float bias = b2f(brel[col]);
        #pragma unroll
        for (int i = 0; i < 4; ++i) {
            const int lrow = quad * 4 + i;
            float v = fmaxf(acc[n][i] + bias, 0.f);
            tile[lrow][col] = f2bf(v);
        }
    }
    __syncthreads();   // tile now holds h for the whole 16-row block

    // ---- Phase 3a: coalesced writeback (16 B/thread, full lines) ----
    const int isF32 = flags[0];
    {
        const int lr2 = tid >> 4;
        const int c16 = tid & 15;
        uint4 v = *(const uint4*)&tile[lr2][c16 * 8];
        ((uint4*)outb)[(size_t)(m0 + lr2) * 16 + c16] = v;
        if (outG) {
            if (isF32) {
                float4* p = (float4*)outG + 160 + (size_t)(m0 + lr2) * 32 + c16 * 2;
                p[0] = (float4){bflo(v.x), bfhi(v.x), bflo(v.y), bfhi(v.y)};
                p[1] = (float4){bflo(v.z), bfhi(v.z), bflo(v.w), bfhi(v.w)};
            } else {
                uint4* p = (uint4*)((unsigned short*)outG + 640);
                p[(size_t)(m0 + lr2) * 16 + c16] = v;
            }
        }
    }

    // ---- Phase 3b: pool; dense partial for first-graph run, atomics only
    //      for boundary-crossing runs ----
    if (tid < 128) {
        const int col = tid;
        const int slice = blockIdx.x & 7;
        int rr = 0;
        float mx = 0.f, sm = 0.f;
        if (ppart) {
            const int g0 = sbatch[0];
            for (; rr < 16 && sbatch[rr] == g0; ++rr) {
                float v = b2f(tile[rr][col]);
                mx = fmaxf(mx, v); sm += v;
            }
            ppart[(size_t)blockIdx.x * 128 + col] =
                (unsigned)f2bf(mx) | ((unsigned)f2bf(sm) << 16);
            mx = 0.f; sm = 0.f;
        }
        if (rr < 16) {
            int curg = sbatch[rr];
            for (; rr < 16; ++rr) {
                int g = sbatch[rr];
                if (g != curg) {
                    atomicMax(&pmx[(slice * GG + curg) * 128 + col], __float_as_uint(mx));
                    unsafeAtomicAdd(&psum[(slice * GG + curg) * 128 + col], sm);
                    curg = g; mx = 0.f; sm = 0.f;
                }
                float v = b2f(tile[rr][col]);
                mx = fmaxf(mx, v);
                sm += v;
            }
            atomicMax(&pmx[(slice * GG + curg) * 128 + col], __float_as_uint(mx));
            unsafeAtomicAdd(&psum[(slice * GG + curg) * 128 + col], sm);
        }
    }
}

// -------------------------------------------------------------------------
// MLP head: ge = atomic slices (boundary runs) + dense per-block partials
// (packed bf16 {mx,sm}) over each graph's block range; gstart table replaces
// the serial binary searches.
// -------------------------------------------------------------------------
__global__ __launch_bounds__(256) void mlp_kernel(const unsigned* __restrict__ pmxL,
                                                  const float* __restrict__ psum,
                                                  const unsigned* __restrict__ part, // [3][3125][128] u32 or null
                                                  const int* __restrict__ gstart,
                                                  const unsigned short* __restrict__ W1,
                                                  const unsigned short* __restrict__ b1,
                                                  const unsigned short* __restrict__ W2,
                                                  const unsigned short* __restrict__ b2,
                                                  const unsigned short* __restrict__ W3,
                                                  const unsigned short* __restrict__ b3,
                                                  void* __restrict__ out,
                                                  const int* __restrict__ flags) {
    int g = blockIdx.x;
    int t = threadIdx.x;
    int isF32 = flags[0];
    __shared__ float sge[256];
    __shared__ float sz1[128];
    __shared__ float sz2[64];

    int start = gstart[g];
    int end   = gstart[g + 1];
    int cnt   = end - start;

    int b_lo = (start + 15) >> 4;
    int b_hi = (cnt > 0) ? ((end - 1) >> 4) : (b_lo - 1);

    float v;
    if (t < 128) {
        v = 0.f;
        #pragma unroll
        for (int L = 0; L < 3; ++L) {
            float m = 0.f;
            #pragma unroll
            for (int s = 0; s < 8; ++s)
                m = fmaxf(m, __uint_as_float(pmxL[((L * 8 + s) * GG + g) * 128 + t]));
            if (part) {
                const unsigned* pm = part + (size_t)L * PARTN * 128;
                for (int b = b_lo; b <= b_hi; ++b)
                    m = fmaxf(m, b2f((unsigned short)(pm[(size_t)b * 128 + t] & 0xffffu)));
            }
            v += m;
        }
    } else {
        float sm = 0.f;
        #pragma unroll
        for (int s = 0; s < 8; ++s) sm += psum[(s * GG + g) * 128 + (t - 128)];
        if (part) {
            #pragma unroll
            for (int L = 0; L < 3; ++L) {
                const unsigned* pm = part + (size_t)L * PARTN * 128;
                for (int b = b_lo; b <= b_hi; ++b)
                    sm += b2f((unsigned short)(pm[(size_t)b * 128 + (t - 128)] >> 16));
            }
        }
        v = sm / fmaxf((float)cnt, 1.f);
    }
    sge[t] = v;
    size_t geo = (size_t)640 + (size_t)NN * 128 + (size_t)g * 256 + t;
    if (isF32) ((float*)out)[geo] = v;
    else       ((unsigned short*)out)[geo] = f2bf(v);
    __syncthreads();

    if (t < 128) {
        float acc = b2f(b1[t]);
        for (int k = 0; k < 256; ++k) acc = fmaf(sge[k], b2f(W1[t * 256 + k]), acc);
        sz1[t] = fmaxf(acc, 0.f);
    }
    __syncthreads();
    if (t < 64) {
        float acc = b2f(b2[t]);
        for (int k = 0; k < 128; ++k) acc = fmaf(sz1[k], b2f(W2[t * 128 + k]), acc);
        sz2[t] = fmaxf(acc, 0.f);
    }
    __syncthreads();
    if (t < 10) {
        float acc = b2f(b3[t]);
        for (int k = 0; k < 64; ++k) acc = fmaf(sz2[k], b2f(W3[t * 64 + k]), acc);
        size_t o = (size_t)g * 10 + t;
        if (isF32) ((float*)out)[o] = acc;
        else       ((unsigned short*)out)[o] = f2bf(acc);
    }
}

// ---- bf16 arena element offsets ----
#define XBF_OFF   0            // x, then h3
#define HA_OFF    6400000      // h1
#define HB_OFF    12800000     // h2
#define WR1_OFF   19200000
#define WO1_OFF   19216384
#define BR1_OFF   19232768
#define WR2_OFF   19232896
#define WO2_OFF   19249280
#define BR2_OFF   19265664
#define WR3_OFF   19265792
#define WO3_OFF   19282176
#define BR3_OFF   19298560
#define W1_OFF    19298688
#define B1_OFF    19331456
#define W2_OFF    19331584
#define B2_OFF    19339776
#define W3_OFF    19339840
#define B3_OFF    19340480
#define ARENA_END 19340490

extern "C" void kernel_launch(void* const* d_in, const int* in_sizes, int n_in,
                              void* d_out, int out_size, void* d_ws, size_t ws_size,
                              hipStream_t stream) {
    unsigned short* arena = (unsigned short*)d_ws;
    size_t intBase = ((size_t)ARENA_END * 2 + 255) & ~(size_t)255;
    char* ib = (char*)d_ws + intBase;
    // compacted int-region layout (csr_src now u16):
    int*            row_ptr = (int*)ib;                        //   200,064 B
    unsigned short* csr_src = (unsigned short*)(ib + 200064);  // 1,600,000 B
    unsigned*       packed  = (unsigned*)(ib + 1800064);       // 3,200,000 B
    int*            counts  = (int*)(ib + 5000064);            //   128,000 B
    int*            offsets = (int*)(ib + 5128064);            //   128,000 B
    int*            bbase   = (int*)(ib + 5256064);            //     1,028 B (pad to 5,257,216)
    unsigned*       pmxL    = (unsigned*)(ib + 5257216);       //   786,432 B [3][8][64][128]
    float*          psum    = (float*)(ib + 6043648);          //   262,144 B [8][64][128]
    int*            flags   = (int*)(ib + 6305792);            //         8 B (pad to 6,305,920)
    int*            gstart  = (int*)(ib + 6305920);            //       260 B (pad to 6,306,304)
    unsigned*       part    = (unsigned*)(ib + 6306304);       // 4,800,000 B [3][3125][128] u32

    size_t need = intBase + 6306304 + (size_t)3 * PARTN * 128 * 4;   // ~49.8 MB
    unsigned* partP = (ws_size >= need) ? part : nullptr;

    const unsigned* eiw = (const unsigned*)d_in[1];
    const unsigned* bw  = (const unsigned*)d_in[2];
    dim3 blk(256);

    detect_kernel<<<1, 256, 0, stream>>>((const unsigned*)d_in[0], eiw, flags);

    // Mega prep: convert x + weights + bucket_count + zero pool slices (1 MiB).
    WPtrs wp;
    for (int i = 0; i < 15; ++i) wp.p[i] = d_in[3 + i];
    prep_kernel<<<4055, blk, 0, stream>>>(d_in[0], eiw, wp, arena, counts,
                                          (uint4*)pmxL, flags);

    // CSR build (+ gstart table in bucket_offsets' idle block)
    bucket_offsets<<<1, blk, 0, stream>>>(counts, offsets, bbase, bw, gstart, flags);
    bucket_scatter<<<ABLOCKS, blk, 0, stream>>>(eiw, offsets, packed, flags);
    bucket_sort<<<NBUCK, blk, 0, stream>>>(packed, bbase, csr_src, row_ptr);

    const int convGrid = NN / 16;             // 3125

    // ---- Layer 1: x(X) -> h1(HA) ----
    conv_fused<<<convGrid, blk, 0, stream>>>(arena + XBF_OFF, row_ptr, csr_src,
                                             arena + WR1_OFF, arena + WO1_OFF, arena + BR1_OFF,
                                             bw, pmxL, psum,
                                             partP,
                                             arena + HA_OFF, nullptr, flags);
    // ---- Layer 2: h1(HA) -> h2(HB) ----
    conv_fused<<<convGrid, blk, 0, stream>>>(arena + HA_OFF, row_ptr, csr_src,
                                             arena + WR2_OFF, arena + WO2_OFF, arena + BR2_OFF,
                                             bw, pmxL + 65536, psum,
                                             partP ? partP + (size_t)PARTN * 128 : nullptr,
                                             arena + HB_OFF, nullptr, flags);
    // ---- Layer 3: h2(HB) -> h3(X slot) + node_embs to d_out ----
    conv_fused<<<convGrid, blk, 0, stream>>>(arena + HB_OFF, row_ptr, csr_src,
                                             arena + WR3_OFF, arena + WO3_OFF, arena + BR3_OFF,
                                             bw, pmxL + 131072, psum,
                                             partP ? partP + (size_t)2 * PARTN * 128 : nullptr,
                                             arena + XBF_OFF, d_out, flags);

    mlp_kernel<<<GG, blk, 0, stream>>>(pmxL, psum, partP, gstart,
                                       arena + W1_OFF, arena + B1_OFF,
                                       arena + W2_OFF, arena + B2_OFF,
                                       arena + W3_OFF, arena + B3_OFF, d_out, flags);
}

// Round 4
// 350.963 us; speedup vs baseline: 1.1552x; 1.1552x over previous
//
#include <hip/hip_runtime.h>
#include <hip/hip_bf16.h>

#define NN 50000
#define EE 800000
#define GG 64
#define NBUCK 196              // ceil(NN/256)
#define ABLOCKS 125            // edge chunks: 125 x 6400 = 800000
#define CHUNK 6400
#define BCAP 8192              // LDS bucket capacity (mean 4096, sd ~64)
#define SPANCAP 512            // per-block (16-row) staged CSR index cap; mean 256, sd 16
#define PARTN 3125             // conv grid blocks (NN/16)

typedef __attribute__((ext_vector_type(8))) short bf16x8;
typedef __attribute__((ext_vector_type(4))) float f32x4;

// ---- bf16 helpers ----
__device__ __forceinline__ float bflo(unsigned u) { return __uint_as_float(u << 16); }
__device__ __forceinline__ float bfhi(unsigned u) { return __uint_as_float(u & 0xffff0000u); }
__device__ __forceinline__ float b2f(unsigned short s) { return __uint_as_float(((unsigned)s) << 16); }
__device__ __forceinline__ unsigned short f2bf(float f) {
    __hip_bfloat16 h = __float2bfloat16(f);
    union { __hip_bfloat16 h; unsigned short u; } cv; cv.h = h; return cv.u;
}

// -------------------------------------------------------------------------
// Detector (verified r2-r9): flags[0]=fp32? flags[1]=int64?
// Also inits gstart[0..64]=NN (prep's parallel gstart pass fills boundaries).
// -------------------------------------------------------------------------
__global__ void detect_kernel(const unsigned* __restrict__ xw,
                              const unsigned* __restrict__ eiw,
                              int* __restrict__ flags,
                              int* __restrict__ gstart) {
    __shared__ int s_cnt, s_nz;
    if (threadIdx.x == 0) { s_cnt = 0; s_nz = 0; }
    if (threadIdx.x < 65) gstart[threadIdx.x] = NN;
    __syncthreads();
    int cnt = 0;
    for (int i = threadIdx.x; i < 4096; i += 256) {
        unsigned w = xw[(size_t)i * 711];
        unsigned elo = (w >> 7) & 0xFF;
        if (elo >= 100 && elo <= 140) cnt++;
    }
    int nz = 0;
    for (int i = threadIdx.x; i < 1024; i += 256) {
        unsigned w = eiw[(size_t)i * 1560 + 1];
        if (w != 0) nz++;
    }
    atomicAdd(&s_cnt, cnt);
    atomicAdd(&s_nz, nz);
    __syncthreads();
    if (threadIdx.x == 0) {
        flags[0] = (s_cnt < 3600) ? 1 : 0;
        flags[1] = (s_nz  < 8)    ? 1 : 0;
    }
}

// -------------------------------------------------------------------------
// Mega prep: [0,3125) convert x; [3125,3674) convert weights;
// [3674,3799) bucket_count; [3799,4055) zero pool slices (1 MiB);
// [4055,4251) parallel gstart boundary scan (one thread per node).
// -------------------------------------------------------------------------
struct WPtrs { const void* p[15]; };

__global__ __launch_bounds__(256) void prep_kernel(const void* __restrict__ xsrc,
                                                   const unsigned* __restrict__ eiw,
                                                   const unsigned* __restrict__ bw,
                                                   WPtrs wp,
                                                   unsigned short* __restrict__ arena,
                                                   int* __restrict__ counts,
                                                   uint4* __restrict__ zero_region,
                                                   int* __restrict__ gstart,
                                                   const int* __restrict__ flags) {
    const int b = blockIdx.x;
    const int tid = threadIdx.x;
    const int isF32 = flags[0];

    if (b < 3125) {
        const int total4 = NN * 128 / 4;   // 1,600,000
        for (int i = b * 256 + tid; i < total4; i += 800000) {
            uint2 o;
            if (isF32) {
                float4 f = ((const float4*)xsrc)[i];
                o.x = (unsigned)f2bf(f.x) | ((unsigned)f2bf(f.y) << 16);
                o.y = (unsigned)f2bf(f.z) | ((unsigned)f2bf(f.w) << 16);
            } else {
                o = ((const uint2*)xsrc)[i];
            }
            ((uint2*)arena)[i] = o;
        }
    } else if (b < 3674) {
        const int cnt[15] = {16384,128,16384, 16384,128,16384, 16384,128,16384,
                             32768,128,8192,64,640,10};
        const int dst[15] = {19200000,19232768,19216384, 19232896,19265664,19249280,
                             19265792,19298560,19282176,
                             19298688,19331456,19331584,19339776,19339840,19340480};
        const int total = 140490;
        int i = (b - 3125) * 256 + tid;
        if (i < total) {
            int seg = 0, base = 0;
            while (i - base >= cnt[seg]) { base += cnt[seg]; ++seg; }
            int off = i - base;
            const void* s = wp.p[seg];
            arena[dst[seg] + off] =
                isF32 ? f2bf(((const float*)s)[off]) : ((const unsigned short*)s)[off];
        }
    } else if (b < 3799) {
        __shared__ int hist[256];
        hist[tid] = 0;
        __syncthreads();
        const int i64 = flags[1];
        const int e0 = (b - 3674) * CHUNK;
        for (int it = 0; it < CHUNK / 256; ++it) {
            int e = e0 + it * 256 + tid;
            int d = (int)(i64 ? eiw[(size_t)2 * (EE + e)] : eiw[EE + e]);
            atomicAdd(&hist[d >> 8], 1);
        }
        __syncthreads();
        counts[(b - 3674) * 256 + tid] = hist[tid];
    } else if (b < 4055) {
        // zero pool accumulators: 256 blocks x 256 thr x 16 B = 1,048,576 B
        zero_region[(b - 3799) * 256 + tid] = (uint4){0, 0, 0, 0};
    } else {
        // parallel gstart: one thread per node, write boundary transitions
        const int i64 = flags[1];
        int i = (b - 4055) * 256 + tid;
        if (i < NN) {
            int g  = (int)(i64 ? bw[(size_t)2 * i] : bw[i]);
            int gp = (i == 0) ? -1 : (int)(i64 ? bw[(size_t)2 * (i - 1)] : bw[i - 1]);
            for (int gg = gp + 1; gg <= g; ++gg) gstart[gg] = i;   // unique writer per gg
        }
    }
}

// -------------------------------------------------------------------------
// CSR build via 2-level bucket sort (verified r6-r9).
// -------------------------------------------------------------------------
__global__ __launch_bounds__(256) void bucket_offsets(const int* __restrict__ counts,
                                                      int* __restrict__ offsets,
                                                      int* __restrict__ bucket_base) {
    __shared__ int s[256];
    const int t = threadIdx.x;
    int col = 0;
    for (int b = 0; b < ABLOCKS; ++b) col += counts[b * 256 + t];
    s[t] = col;
    __syncthreads();
    for (int d = 1; d < 256; d <<= 1) {
        int x = (t >= d) ? s[t - d] : 0;
        __syncthreads();
        s[t] += x;
        __syncthreads();
    }
    int base = s[t] - col;
    bucket_base[t] = base;
    if (t == 255) bucket_base[256] = s[255];
    int run = base;
    for (int b = 0; b < ABLOCKS; ++b) {
        offsets[b * 256 + t] = run;
        run += counts[b * 256 + t];
    }
}

__global__ __launch_bounds__(256) void bucket_scatter(const unsigned* __restrict__ eiw,
                                                      const int* __restrict__ offsets,
                                                      unsigned* __restrict__ packed,
                                                      const int* __restrict__ flags) {
    __shared__ int cur[256];
    cur[threadIdx.x] = offsets[blockIdx.x * 256 + threadIdx.x];
    __syncthreads();
    int i64 = flags[1];
    int e0 = blockIdx.x * CHUNK;
    for (int it = 0; it < CHUNK / 256; ++it) {
        int e = e0 + it * 256 + threadIdx.x;
        int s = (int)(i64 ? eiw[(size_t)2 * e]        : eiw[e]);
        int d = (int)(i64 ? eiw[(size_t)2 * (EE + e)] : eiw[EE + e]);
        int pos = atomicAdd(&cur[d >> 8], 1);
        packed[pos] = ((unsigned)s << 8) | (unsigned)(d & 255);
    }
}

__global__ __launch_bounds__(256) void bucket_sort(const unsigned* __restrict__ packed,
                                                   const int* __restrict__ bucket_base,
                                                   unsigned short* __restrict__ csr_src,  // u16: src < 65536
                                                   int* __restrict__ row_ptr) {
    __shared__ unsigned sbuf[BCAP];
    __shared__ int hist[256];
    __shared__ int cur[256];
    const int t = threadIdx.x;
    const int b = blockIdx.x;
    const int lo = bucket_base[b];
    int n = bucket_base[b + 1] - lo;
    if (n > BCAP) n = BCAP;

    hist[t] = 0;
    __syncthreads();
    for (int i = t; i < n; i += 256) {
        unsigned p = packed[lo + i];
        sbuf[i] = p;
        atomicAdd(&hist[p & 255], 1);
    }
    __syncthreads();
    int v = hist[t];
    __shared__ int s[256];
    s[t] = v;
    __syncthreads();
    for (int d = 1; d < 256; d <<= 1) {
        int x = (t >= d) ? s[t - d] : 0;
        __syncthreads();
        s[t] += x;
        __syncthreads();
    }
    int start = s[t] - v;
    int node = b * 256 + t;
    if (node < NN) row_ptr[node] = lo + start;
    if (b == 0 && t == 0) row_ptr[NN] = EE;
    cur[t] = start;
    __syncthreads();
    for (int i = t; i < n; i += 256) {
        unsigned p = sbuf[i];
        int pos = atomicAdd(&cur[p & 255], 1);
        csr_src[lo + pos] = (unsigned short)(p >> 8);
    }
}

// -------------------------------------------------------------------------
// Fused conv v6 (unchanged from r3 — keeping config stable to read its
// counters cleanly this round):
//  - gather 16-deep + 8 + predicated tail; launch_bounds(256,4).
//  - root-row A-frags hoisted before phase 1.
//  - csr indices u16.
//  - pool: dense per-block partial {mx,sm} packed bf16 (non-atomic) for the
//    first-graph run; atomics only for boundary-crossing runs.
// -------------------------------------------------------------------------
__global__ __launch_bounds__(256, 4) void conv_fused(const unsigned short* __restrict__ hin,
                                                     const int* __restrict__ row_ptr,
                                                     const unsigned short* __restrict__ csr16,
                                                     const unsigned short* __restrict__ Wrel,
                                                     const unsigned short* __restrict__ Wroot,
                                                     const unsigned short* __restrict__ brel,
                                                     const unsigned* __restrict__ bw,
                                                     unsigned* __restrict__ pmx,   // layer's [8][64][128]
                                                     float* __restrict__ psum,     // [8][64][128] (shared)
                                                     unsigned* __restrict__ ppart, // layer's [3125][128] u32 or null
                                                     unsigned short* __restrict__ outb,
                                                     void* __restrict__ outG,
                                                     const int* __restrict__ flags) {
    __shared__ __align__(16) unsigned short tile[16][136];   // 4.25 KB
    __shared__ int sbatch[16];
    __shared__ int s_rp[17];
    __shared__ unsigned short s_idx[SPANCAP];                // 1 KB

    const int tid  = threadIdx.x;
    const int wv   = tid >> 6;
    const int lane = tid & 63;
    const int m0   = blockIdx.x * 16;
    const int mrow = lane & 15;
    const int quad = lane >> 4;

    // ---- Phase 0: stage row_ptr + CSR indices; sbatch piggybacks ----
    if (tid < 17) s_rp[tid] = row_ptr[m0 + tid];
    if (tid >= 32 && tid < 48) {
        const int i64 = flags[1];
        int rr = m0 + (tid - 32);
        sbatch[tid - 32] = (int)(i64 ? bw[(size_t)2 * rr] : bw[rr]);
    }
    __syncthreads();
    const int base = s_rp[0];
    const int span = s_rp[16] - base;
    const int nst  = (span < SPANCAP) ? span : SPANCAP;
    for (int i = tid; i < nst; i += 256) s_idx[i] = csr16[base + i];

    // ---- root-row A-frag hoist (consumed in phase 2, kk=4..7) ----
    bf16x8 rootv[4];
    #pragma unroll
    for (int k2 = 0; k2 < 4; ++k2)
        rootv[k2] = *(const bf16x8*)(hin + (size_t)(m0 + mrow) * 128 + k2 * 32 + quad * 8);

    __syncthreads();

    // ---- Phase 1: gather, quad-per-row, uint4 per lane, 16-deep ----
    const int qd  = lane >> 4;        // which of the wave's 4 rows
    const int l16 = lane & 15;        // channel block: [l16*8, l16*8+8)
    const int lr  = wv * 4 + qd;
    const int jb  = s_rp[lr]     - base;
    const int je  = s_rp[lr + 1] - base;
    const uint4* h16 = (const uint4*)hin;   // 16 uint4 per 128-ch row

    float a0 = 0.f, a1 = 0.f, a2 = 0.f, a3 = 0.f,
          a4 = 0.f, a5 = 0.f, a6 = 0.f, a7 = 0.f;

    if (span <= SPANCAP) {
        int j = jb;
        for (; j + 16 <= je; j += 16) {      // 16 loads in flight
            int idx[16];
            #pragma unroll
            for (int q = 0; q < 16; ++q) idx[q] = s_idx[j + q];
            uint4 u[16];
            #pragma unroll
            for (int q = 0; q < 16; ++q) u[q] = h16[(size_t)idx[q] * 16 + l16];
            #pragma unroll
            for (int q = 0; q < 16; ++q) {
                a0 += bflo(u[q].x); a1 += bfhi(u[q].x);
                a2 += bflo(u[q].y); a3 += bfhi(u[q].y);
                a4 += bflo(u[q].z); a5 += bfhi(u[q].z);
                a6 += bflo(u[q].w); a7 += bfhi(u[q].w);
            }
        }
        if (j + 8 <= je) {                   // one 8-deep batch
            int idx[8];
            #pragma unroll
            for (int q = 0; q < 8; ++q) idx[q] = s_idx[j + q];
            uint4 u[8];
            #pragma unroll
            for (int q = 0; q < 8; ++q) u[q] = h16[(size_t)idx[q] * 16 + l16];
            #pragma unroll
            for (int q = 0; q < 8; ++q) {
                a0 += bflo(u[q].x); a1 += bfhi(u[q].x);
                a2 += bflo(u[q].y); a3 += bfhi(u[q].y);
                a4 += bflo(u[q].z); a5 += bfhi(u[q].z);
                a6 += bflo(u[q].w); a7 += bfhi(u[q].w);
            }
            j += 8;
        }
        if (j < je) {                        // one predicated tail batch
            #pragma unroll
            for (int q = 0; q < 8; ++q) {
                int ii = j + q;
                int ic = (ii < je - 1) ? ii : (je - 1);
                float sc = (ii < je) ? 1.f : 0.f;
                uint4 u = h16[(size_t)s_idx[ic] * 16 + l16];
                a0 = fmaf(bflo(u.x), sc, a0); a1 = fmaf(bfhi(u.x), sc, a1);
                a2 = fmaf(bflo(u.y), sc, a2); a3 = fmaf(bfhi(u.y), sc, a3);
                a4 = fmaf(bflo(u.z), sc, a4); a5 = fmaf(bfhi(u.z), sc, a5);
                a6 = fmaf(bflo(u.w), sc, a6); a7 = fmaf(bfhi(u.w), sc, a7);
            }
        }
    } else {
        // pathological span (never expected for this input): global indices
        for (int j = jb; j < je; j += 8) {
            #pragma unroll
            for (int q = 0; q < 8; ++q) {
                int ii = j + q;
                int ic = (ii < je - 1) ? ii : (je - 1);
                float sc = (ii < je) ? 1.f : 0.f;
                uint4 u = h16[(size_t)csr16[base + ic] * 16 + l16];
                a0 = fmaf(bflo(u.x), sc, a0); a1 = fmaf(bfhi(u.x), sc, a1);
                a2 = fmaf(bflo(u.y), sc, a2); a3 = fmaf(bfhi(u.y), sc, a3);
                a4 = fmaf(bflo(u.z), sc, a4); a5 = fmaf(bfhi(u.z), sc, a5);
                a6 = fmaf(bflo(u.w), sc, a6); a7 = fmaf(bfhi(u.w), sc, a7);
            }
        }
    }

    {
        uint4 o;
        o.x = (unsigned)f2bf(a0) | ((unsigned)f2bf(a1) << 16);
        o.y = (unsigned)f2bf(a2) | ((unsigned)f2bf(a3) << 16);
        o.z = (unsigned)f2bf(a4) | ((unsigned)f2bf(a5) << 16);
        o.w = (unsigned)f2bf(a6) | ((unsigned)f2bf(a7) << 16);
        *(uint4*)&tile[lr][l16 * 8] = o;
    }
    __syncthreads();

    // ---- Phase 2: MFMA GEMM, wave owns a 32-col slice ----
    f32x4 acc[2];
    acc[0] = (f32x4){0.f, 0.f, 0.f, 0.f};
    acc[1] = (f32x4){0.f, 0.f, 0.f, 0.f};

    #pragma unroll
    for (int kk = 0; kk < 8; ++kk) {
        const unsigned short* Bs = (kk < 4) ? Wrel : Wroot;
        const int kc = (kk & 3) * 32 + quad * 8;
        bf16x8 a;
        if (kk < 4) a = *(const bf16x8*)&tile[mrow][kc];
        else        a = rootv[kk - 4];
        #pragma unroll
        for (int n = 0; n < 2; ++n) {
            const int col0 = (wv * 2 + n) * 16;
            bf16x8 b = *(const bf16x8*)(Bs + (size_t)(col0 + mrow) * 128 + kc);
            acc[n] = __builtin_amdgcn_mfma_f32_16x16x32_bf16(a, b, acc[n], 0, 0, 0);
        }
    }

    __syncthreads();   // RACE FIX: all agg A-frag reads complete before h overwrites tile

    #pragma unroll
    for (int n = 0; n < 2; ++n) {
        const int col = (wv * 2 + n) * 16 + mrow;
        const float bias = b2f(brel[col]);
        #pragma unroll
        for (int i = 0; i < 4; ++i) {
            const int lrow = quad * 4 + i;
            float v = fmaxf(acc[n][i] + bias, 0.f);
            tile[lrow][col] = f2bf(v);
        }
    }
    __syncthreads();   // tile now holds h for the whole 16-row block

    // ---- Phase 3a: coalesced writeback (16 B/thread, full lines) ----
    const int isF32 = flags[0];
    {
        const int lr2 = tid >> 4;
        const int c16 = tid & 15;
        uint4 v = *(const uint4*)&tile[lr2][c16 * 8];
        ((uint4*)outb)[(size_t)(m0 + lr2) * 16 + c16] = v;
        if (outG) {
            if (isF32) {
                float4* p = (float4*)outG + 160 + (size_t)(m0 + lr2) * 32 + c16 * 2;
                p[0] = (float4){bflo(v.x), bfhi(v.x), bflo(v.y), bfhi(v.y)};
                p[1] = (float4){bflo(v.z), bfhi(v.z), bflo(v.w), bfhi(v.w)};
            } else {
                uint4* p = (uint4*)((unsigned short*)outG + 640);
                p[(size_t)(m0 + lr2) * 16 + c16] = v;
            }
        }
    }

    // ---- Phase 3b: pool; dense partial for first-graph run, atomics only
    //      for boundary-crossing runs ----
    if (tid < 128) {
        const int col = tid;
        const int slice = blockIdx.x & 7;
        int rr = 0;
        float mx = 0.f, sm = 0.f;
        if (ppart) {
            const int g0 = sbatch[0];
            for (; rr < 16 && sbatch[rr] == g0; ++rr) {
                float v = b2f(tile[rr][col]);
                mx = fmaxf(mx, v); sm += v;
            }
            ppart[(size_t)blockIdx.x * 128 + col] =
                (unsigned)f2bf(mx) | ((unsigned)f2bf(sm) << 16);
            mx = 0.f; sm = 0.f;
        }
        if (rr < 16) {
            int curg = sbatch[rr];
            for (; rr < 16; ++rr) {
                int g = sbatch[rr];
                if (g != curg) {
                    atomicMax(&pmx[(slice * GG + curg) * 128 + col], __float_as_uint(mx));
                    unsafeAtomicAdd(&psum[(slice * GG + curg) * 128 + col], sm);
                    curg = g; mx = 0.f; sm = 0.f;
                }
                float v = b2f(tile[rr][col]);
                mx = fmaxf(mx, v);
                sm += v;
            }
            atomicMax(&pmx[(slice * GG + curg) * 128 + col], __float_as_uint(mx));
            unsafeAtomicAdd(&psum[(slice * GG + curg) * 128 + col], sm);
        }
    }
}

// -------------------------------------------------------------------------
// MLP head: ge = atomic slices (boundary runs) + dense per-block partials
// (packed bf16 {mx,sm}) over each graph's block range; gstart table replaces
// the serial binary searches.
// -------------------------------------------------------------------------
__global__ __launch_bounds__(256) void mlp_kernel(const unsigned* __restrict__ pmxL,
                                                  const float* __restrict__ psum,
                                                  const unsigned* __restrict__ part, // [3][3125][128] u32 or null
                                                  const int* __restrict__ gstart,
                                                  const unsigned short* __restrict__ W1,
                                                  const unsigned short* __restrict__ b1,
                                                  const unsigned short* __restrict__ W2,
                                                  const unsigned short* __restrict__ b2,
                                                  const unsigned short* __restrict__ W3,
                                                  const unsigned short* __restrict__ b3,
                                                  void* __restrict__ out,
                                                  const int* __restrict__ flags) {
    int g = blockIdx.x;
    int t = threadIdx.x;
    int isF32 = flags[0];
    __shared__ float sge[256];
    __shared__ float sz1[128];
    __shared__ float sz2[64];

    int start = gstart[g];
    int end   = gstart[g + 1];
    int cnt   = end - start;

    int b_lo = (start + 15) >> 4;
    int b_hi = (cnt > 0) ? ((end - 1) >> 4) : (b_lo - 1);

    float v;
    if (t < 128) {
        v = 0.f;
        #pragma unroll
        for (int L = 0; L < 3; ++L) {
            float m = 0.f;
            #pragma unroll
            for (int s = 0; s < 8; ++s)
                m = fmaxf(m, __uint_as_float(pmxL[((L * 8 + s) * GG + g) * 128 + t]));
            if (part) {
                const unsigned* pm = part + (size_t)L * PARTN * 128;
                for (int b = b_lo; b <= b_hi; ++b)
                    m = fmaxf(m, b2f((unsigned short)(pm[(size_t)b * 128 + t] & 0xffffu)));
            }
            v += m;
        }
    } else {
        float sm = 0.f;
        #pragma unroll
        for (int s = 0; s < 8; ++s) sm += psum[(s * GG + g) * 128 + (t - 128)];
        if (part) {
            #pragma unroll
            for (int L = 0; L < 3; ++L) {
                const unsigned* pm = part + (size_t)L * PARTN * 128;
                for (int b = b_lo; b <= b_hi; ++b)
                    sm += b2f((unsigned short)(pm[(size_t)b * 128 + (t - 128)] >> 16));
            }
        }
        v = sm / fmaxf((float)cnt, 1.f);
    }
    sge[t] = v;
    size_t geo = (size_t)640 + (size_t)NN * 128 + (size_t)g * 256 + t;
    if (isF32) ((float*)out)[geo] = v;
    else       ((unsigned short*)out)[geo] = f2bf(v);
    __syncthreads();

    if (t < 128) {
        float acc = b2f(b1[t]);
        for (int k = 0; k < 256; ++k) acc = fmaf(sge[k], b2f(W1[t * 256 + k]), acc);
        sz1[t] = fmaxf(acc, 0.f);
    }
    __syncthreads();
    if (t < 64) {
        float acc = b2f(b2[t]);
        for (int k = 0; k < 128; ++k) acc = fmaf(sz1[k], b2f(W2[t * 128 + k]), acc);
        sz2[t] = fmaxf(acc, 0.f);
    }
    __syncthreads();
    if (t < 10) {
        float acc = b2f(b3[t]);
        for (int k = 0; k < 64; ++k) acc = fmaf(sz2[k], b2f(W3[t * 64 + k]), acc);
        size_t o = (size_t)g * 10 + t;
        if (isF32) ((float*)out)[o] = acc;
        else       ((unsigned short*)out)[o] = f2bf(acc);
    }
}

// ---- bf16 arena element offsets ----
#define XBF_OFF   0            // x, then h3
#define HA_OFF    6400000      // h1
#define HB_OFF    12800000     // h2
#define WR1_OFF   19200000
#define WO1_OFF   19216384
#define BR1_OFF   19232768
#define WR2_OFF   19232896
#define WO2_OFF   19249280
#define BR2_OFF   19265664
#define WR3_OFF   19265792
#define WO3_OFF   19282176
#define BR3_OFF   19298560
#define W1_OFF    19298688
#define B1_OFF    19331456
#define W2_OFF    19331584
#define B2_OFF    19339776
#define W3_OFF    19339840
#define B3_OFF    19340480
#define ARENA_END 19340490

extern "C" void kernel_launch(void* const* d_in, const int* in_sizes, int n_in,
                              void* d_out, int out_size, void* d_ws, size_t ws_size,
                              hipStream_t stream) {
    unsigned short* arena = (unsigned short*)d_ws;
    size_t intBase = ((size_t)ARENA_END * 2 + 255) & ~(size_t)255;
    char* ib = (char*)d_ws + intBase;
    // compacted int-region layout (csr_src u16):
    int*            row_ptr = (int*)ib;                        //   200,064 B
    unsigned short* csr_src = (unsigned short*)(ib + 200064);  // 1,600,000 B
    unsigned*       packed  = (unsigned*)(ib + 1800064);       // 3,200,000 B
    int*            counts  = (int*)(ib + 5000064);            //   128,000 B
    int*            offsets = (int*)(ib + 5128064);            //   128,000 B
    int*            bbase   = (int*)(ib + 5256064);            //     1,028 B (pad to 5,257,216)
    unsigned*       pmxL    = (unsigned*)(ib + 5257216);       //   786,432 B [3][8][64][128]
    float*          psum    = (float*)(ib + 6043648);          //   262,144 B [8][64][128]
    int*            flags   = (int*)(ib + 6305792);            //         8 B (pad to 6,305,920)
    int*            gstart  = (int*)(ib + 6305920);            //       260 B (pad to 6,306,304)
    unsigned*       part    = (unsigned*)(ib + 6306304);       // 4,800,000 B [3][3125][128] u32

    size_t need = intBase + 6306304 + (size_t)3 * PARTN * 128 * 4;   // ~49.8 MB
    unsigned* partP = (ws_size >= need) ? part : nullptr;

    const unsigned* eiw = (const unsigned*)d_in[1];
    const unsigned* bw  = (const unsigned*)d_in[2];
    dim3 blk(256);

    detect_kernel<<<1, 256, 0, stream>>>((const unsigned*)d_in[0], eiw, flags, gstart);

    // Mega prep: convert x + weights + bucket_count + zero pool + gstart.
    WPtrs wp;
    for (int i = 0; i < 15; ++i) wp.p[i] = d_in[3 + i];
    prep_kernel<<<4251, blk, 0, stream>>>(d_in[0], eiw, bw, wp, arena, counts,
                                          (uint4*)pmxL, gstart, flags);

    // CSR build
    bucket_offsets<<<1, blk, 0, stream>>>(counts, offsets, bbase);
    bucket_scatter<<<ABLOCKS, blk, 0, stream>>>(eiw, offsets, packed, flags);
    bucket_sort<<<NBUCK, blk, 0, stream>>>(packed, bbase, csr_src, row_ptr);

    const int convGrid = NN / 16;             // 3125

    // ---- Layer 1: x(X) -> h1(HA) ----
    conv_fused<<<convGrid, blk, 0, stream>>>(arena + XBF_OFF, row_ptr, csr_src,
                                             arena + WR1_OFF, arena + WO1_OFF, arena + BR1_OFF,
                                             bw, pmxL, psum,
                                             partP,
                                             arena + HA_OFF, nullptr, flags);
    // ---- Layer 2: h1(HA) -> h2(HB) ----
    conv_fused<<<convGrid, blk, 0, stream>>>(arena + HA_OFF, row_ptr, csr_src,
                                             arena + WR2_OFF, arena + WO2_OFF, arena + BR2_OFF,
                                             bw, pmxL + 65536, psum,
                                             partP ? partP + (size_t)PARTN * 128 : nullptr,
                                             arena + HB_OFF, nullptr, flags);
    // ---- Layer 3: h2(HB) -> h3(X slot) + node_embs to d_out ----
    conv_fused<<<convGrid, blk, 0, stream>>>(arena + HB_OFF, row_ptr, csr_src,
                                             arena + WR3_OFF, arena + WO3_OFF, arena + BR3_OFF,
                                             bw, pmxL + 131072, psum,
                                             partP ? partP + (size_t)2 * PARTN * 128 : nullptr,
                                             arena + XBF_OFF, d_out, flags);

    mlp_kernel<<<GG, blk, 0, stream>>>(pmxL, psum, partP, gstart,
                                       arena + W1_OFF, arena + B1_OFF,
                                       arena + W2_OFF, arena + B2_OFF,
                                       arena + W3_OFF, arena + B3_OFF, d_out, flags);
}

// Round 6
// 347.268 us; speedup vs baseline: 1.1675x; 1.0106x over previous
//
#include <hip/hip_runtime.h>
#include <hip/hip_bf16.h>

#define NN 50000
#define EE 800000
#define GG 64
#define NBUCK 196              // ceil(NN/256)
#define ABLOCKS 125            // edge chunks: 125 x 6400 = 800000
#define CHUNK 6400
#define BCAP 8192              // LDS bucket capacity (mean 4096, sd ~64)
#define SPANCAP 512            // per-block (16-row) staged CSR index cap; mean 256, sd 16
#define PARTN 3125             // conv grid blocks (NN/16)

typedef __attribute__((ext_vector_type(8))) short bf16x8;
typedef __attribute__((ext_vector_type(4))) float f32x4;
typedef __attribute__((ext_vector_type(4))) unsigned int u32x4;   // NT-store-compatible

// ---- bf16 helpers ----
__device__ __forceinline__ float bflo(unsigned u) { return __uint_as_float(u << 16); }
__device__ __forceinline__ float bfhi(unsigned u) { return __uint_as_float(u & 0xffff0000u); }
__device__ __forceinline__ float b2f(unsigned short s) { return __uint_as_float(((unsigned)s) << 16); }
__device__ __forceinline__ unsigned short f2bf(float f) {
    __hip_bfloat16 h = __float2bfloat16(f);
    union { __hip_bfloat16 h; unsigned short u; } cv; cv.h = h; return cv.u;
}

// -------------------------------------------------------------------------
// Detector (verified r2-r9): flags[0]=fp32? flags[1]=int64?
// Also inits gstart[0..64]=NN (prep's parallel gstart pass fills boundaries).
// -------------------------------------------------------------------------
__global__ void detect_kernel(const unsigned* __restrict__ xw,
                              const unsigned* __restrict__ eiw,
                              int* __restrict__ flags,
                              int* __restrict__ gstart) {
    __shared__ int s_cnt, s_nz;
    if (threadIdx.x == 0) { s_cnt = 0; s_nz = 0; }
    if (threadIdx.x < 65) gstart[threadIdx.x] = NN;
    __syncthreads();
    int cnt = 0;
    for (int i = threadIdx.x; i < 4096; i += 256) {
        unsigned w = xw[(size_t)i * 711];
        unsigned elo = (w >> 7) & 0xFF;
        if (elo >= 100 && elo <= 140) cnt++;
    }
    int nz = 0;
    for (int i = threadIdx.x; i < 1024; i += 256) {
        unsigned w = eiw[(size_t)i * 1560 + 1];
        if (w != 0) nz++;
    }
    atomicAdd(&s_cnt, cnt);
    atomicAdd(&s_nz, nz);
    __syncthreads();
    if (threadIdx.x == 0) {
        flags[0] = (s_cnt < 3600) ? 1 : 0;
        flags[1] = (s_nz  < 8)    ? 1 : 0;
    }
}

// -------------------------------------------------------------------------
// Mega prep: [0,3125) convert x; [3125,3674) convert weights;
// [3674,3799) bucket_count; [3799,4055) zero pool slices (1 MiB);
// [4055,4251) parallel gstart boundary scan (one thread per node).
// -------------------------------------------------------------------------
struct WPtrs { const void* p[15]; };

__global__ __launch_bounds__(256) void prep_kernel(const void* __restrict__ xsrc,
                                                   const unsigned* __restrict__ eiw,
                                                   const unsigned* __restrict__ bw,
                                                   WPtrs wp,
                                                   unsigned short* __restrict__ arena,
                                                   int* __restrict__ counts,
                                                   uint4* __restrict__ zero_region,
                                                   int* __restrict__ gstart,
                                                   const int* __restrict__ flags) {
    const int b = blockIdx.x;
    const int tid = threadIdx.x;
    const int isF32 = flags[0];

    if (b < 3125) {
        const int total4 = NN * 128 / 4;   // 1,600,000
        for (int i = b * 256 + tid; i < total4; i += 800000) {
            uint2 o;
            if (isF32) {
                float4 f = ((const float4*)xsrc)[i];
                o.x = (unsigned)f2bf(f.x) | ((unsigned)f2bf(f.y) << 16);
                o.y = (unsigned)f2bf(f.z) | ((unsigned)f2bf(f.w) << 16);
            } else {
                o = ((const uint2*)xsrc)[i];
            }
            ((uint2*)arena)[i] = o;
        }
    } else if (b < 3674) {
        const int cnt[15] = {16384,128,16384, 16384,128,16384, 16384,128,16384,
                             32768,128,8192,64,640,10};
        const int dst[15] = {19200000,19232768,19216384, 19232896,19265664,19249280,
                             19265792,19298560,19282176,
                             19298688,19331456,19331584,19339776,19339840,19340480};
        const int total = 140490;
        int i = (b - 3125) * 256 + tid;
        if (i < total) {
            int seg = 0, base = 0;
            while (i - base >= cnt[seg]) { base += cnt[seg]; ++seg; }
            int off = i - base;
            const void* s = wp.p[seg];
            arena[dst[seg] + off] =
                isF32 ? f2bf(((const float*)s)[off]) : ((const unsigned short*)s)[off];
        }
    } else if (b < 3799) {
        __shared__ int hist[256];
        hist[tid] = 0;
        __syncthreads();
        const int i64 = flags[1];
        const int e0 = (b - 3674) * CHUNK;
        for (int it = 0; it < CHUNK / 256; ++it) {
            int e = e0 + it * 256 + tid;
            int d = (int)(i64 ? eiw[(size_t)2 * (EE + e)] : eiw[EE + e]);
            atomicAdd(&hist[d >> 8], 1);
        }
        __syncthreads();
        counts[(b - 3674) * 256 + tid] = hist[tid];
    } else if (b < 4055) {
        // zero pool accumulators: 256 blocks x 256 thr x 16 B = 1,048,576 B
        zero_region[(b - 3799) * 256 + tid] = (uint4){0, 0, 0, 0};
    } else {
        // parallel gstart: one thread per node, write boundary transitions
        const int i64 = flags[1];
        int i = (b - 4055) * 256 + tid;
        if (i < NN) {
            int g  = (int)(i64 ? bw[(size_t)2 * i] : bw[i]);
            int gp = (i == 0) ? -1 : (int)(i64 ? bw[(size_t)2 * (i - 1)] : bw[i - 1]);
            for (int gg = gp + 1; gg <= g; ++gg) gstart[gg] = i;   // unique writer per gg
        }
    }
}

// -------------------------------------------------------------------------
// CSR build via 2-level bucket sort (verified r6-r9).
// -------------------------------------------------------------------------
__global__ __launch_bounds__(256) void bucket_offsets(const int* __restrict__ counts,
                                                      int* __restrict__ offsets,
                                                      int* __restrict__ bucket_base) {
    __shared__ int s[256];
    const int t = threadIdx.x;
    int col = 0;
    for (int b = 0; b < ABLOCKS; ++b) col += counts[b * 256 + t];
    s[t] = col;
    __syncthreads();
    for (int d = 1; d < 256; d <<= 1) {
        int x = (t >= d) ? s[t - d] : 0;
        __syncthreads();
        s[t] += x;
        __syncthreads();
    }
    int base = s[t] - col;
    bucket_base[t] = base;
    if (t == 255) bucket_base[256] = s[255];
    int run = base;
    for (int b = 0; b < ABLOCKS; ++b) {
        offsets[b * 256 + t] = run;
        run += counts[b * 256 + t];
    }
}

__global__ __launch_bounds__(256) void bucket_scatter(const unsigned* __restrict__ eiw,
                                                      const int* __restrict__ offsets,
                                                      unsigned* __restrict__ packed,
                                                      const int* __restrict__ flags) {
    __shared__ int cur[256];
    cur[threadIdx.x] = offsets[blockIdx.x * 256 + threadIdx.x];
    __syncthreads();
    int i64 = flags[1];
    int e0 = blockIdx.x * CHUNK;
    for (int it = 0; it < CHUNK / 256; ++it) {
        int e = e0 + it * 256 + threadIdx.x;
        int s = (int)(i64 ? eiw[(size_t)2 * e]        : eiw[e]);
        int d = (int)(i64 ? eiw[(size_t)2 * (EE + e)] : eiw[EE + e]);
        int pos = atomicAdd(&cur[d >> 8], 1);
        packed[pos] = ((unsigned)s << 8) | (unsigned)(d & 255);
    }
}

__global__ __launch_bounds__(256) void bucket_sort(const unsigned* __restrict__ packed,
                                                   const int* __restrict__ bucket_base,
                                                   unsigned short* __restrict__ csr_src,  // u16: src < 65536
                                                   int* __restrict__ row_ptr) {
    __shared__ unsigned sbuf[BCAP];
    __shared__ int hist[256];
    __shared__ int cur[256];
    const int t = threadIdx.x;
    const int b = blockIdx.x;
    const int lo = bucket_base[b];
    int n = bucket_base[b + 1] - lo;
    if (n > BCAP) n = BCAP;

    hist[t] = 0;
    __syncthreads();
    for (int i = t; i < n; i += 256) {
        unsigned p = packed[lo + i];
        sbuf[i] = p;
        atomicAdd(&hist[p & 255], 1);
    }
    __syncthreads();
    int v = hist[t];
    __shared__ int s[256];
    s[t] = v;
    __syncthreads();
    for (int d = 1; d < 256; d <<= 1) {
        int x = (t >= d) ? s[t - d] : 0;
        __syncthreads();
        s[t] += x;
        __syncthreads();
    }
    int start = s[t] - v;
    int node = b * 256 + t;
    if (node < NN) row_ptr[node] = lo + start;
    if (b == 0 && t == 0) row_ptr[NN] = EE;
    cur[t] = start;
    __syncthreads();
    for (int i = t; i < n; i += 256) {
        unsigned p = sbuf[i];
        int pos = atomicAdd(&cur[p & 255], 1);
        csr_src[lo + pos] = (unsigned short)(p >> 8);
    }
}

// -------------------------------------------------------------------------
// Fused conv v7b = v6 + (a) ws layout fix so dense pool is GUARANTEED active
// (part overlaps dead-after-CSR packed region), (b) non-temporal stores for
// outb/outG via clang ext_vector types (r5 compile fix: HIP uint4/float4
// are struct-wrapped and rejected by __builtin_nontemporal_store).
// -------------------------------------------------------------------------
__global__ __launch_bounds__(256, 4) void conv_fused(const unsigned short* __restrict__ hin,
                                                     const int* __restrict__ row_ptr,
                                                     const unsigned short* __restrict__ csr16,
                                                     const unsigned short* __restrict__ Wrel,
                                                     const unsigned short* __restrict__ Wroot,
                                                     const unsigned short* __restrict__ brel,
                                                     const unsigned* __restrict__ bw,
                                                     unsigned* __restrict__ pmx,   // layer's [8][64][128]
                                                     float* __restrict__ psum,     // [8][64][128] (shared)
                                                     unsigned* __restrict__ ppart, // layer's [3125][128] u32 or null
                                                     unsigned short* __restrict__ outb,
                                                     void* __restrict__ outG,
                                                     const int* __restrict__ flags) {
    __shared__ __align__(16) unsigned short tile[16][136];   // 4.25 KB
    __shared__ int sbatch[16];
    __shared__ int s_rp[17];
    __shared__ unsigned short s_idx[SPANCAP];                // 1 KB

    const int tid  = threadIdx.x;
    const int wv   = tid >> 6;
    const int lane = tid & 63;
    const int m0   = blockIdx.x * 16;
    const int mrow = lane & 15;
    const int quad = lane >> 4;

    // ---- Phase 0: stage row_ptr + CSR indices; sbatch piggybacks ----
    if (tid < 17) s_rp[tid] = row_ptr[m0 + tid];
    if (tid >= 32 && tid < 48) {
        const int i64 = flags[1];
        int rr = m0 + (tid - 32);
        sbatch[tid - 32] = (int)(i64 ? bw[(size_t)2 * rr] : bw[rr]);
    }
    __syncthreads();
    const int base = s_rp[0];
    const int span = s_rp[16] - base;
    const int nst  = (span < SPANCAP) ? span : SPANCAP;
    for (int i = tid; i < nst; i += 256) s_idx[i] = csr16[base + i];

    // ---- root-row A-frag hoist (consumed in phase 2, kk=4..7) ----
    bf16x8 rootv[4];
    #pragma unroll
    for (int k2 = 0; k2 < 4; ++k2)
        rootv[k2] = *(const bf16x8*)(hin + (size_t)(m0 + mrow) * 128 + k2 * 32 + quad * 8);

    __syncthreads();

    // ---- Phase 1: gather, quad-per-row, uint4 per lane, 16-deep ----
    const int qd  = lane >> 4;        // which of the wave's 4 rows
    const int l16 = lane & 15;        // channel block: [l16*8, l16*8+8)
    const int lr  = wv * 4 + qd;
    const int jb  = s_rp[lr]     - base;
    const int je  = s_rp[lr + 1] - base;
    const uint4* h16 = (const uint4*)hin;   // 16 uint4 per 128-ch row

    float a0 = 0.f, a1 = 0.f, a2 = 0.f, a3 = 0.f,
          a4 = 0.f, a5 = 0.f, a6 = 0.f, a7 = 0.f;

    if (span <= SPANCAP) {
        int j = jb;
        for (; j + 16 <= je; j += 16) {      // 16 loads in flight
            int idx[16];
            #pragma unroll
            for (int q = 0; q < 16; ++q) idx[q] = s_idx[j + q];
            uint4 u[16];
            #pragma unroll
            for (int q = 0; q < 16; ++q) u[q] = h16[(size_t)idx[q] * 16 + l16];
            #pragma unroll
            for (int q = 0; q < 16; ++q) {
                a0 += bflo(u[q].x); a1 += bfhi(u[q].x);
                a2 += bflo(u[q].y); a3 += bfhi(u[q].y);
                a4 += bflo(u[q].z); a5 += bfhi(u[q].z);
                a6 += bflo(u[q].w); a7 += bfhi(u[q].w);
            }
        }
        if (j + 8 <= je) {                   // one 8-deep batch
            int idx[8];
            #pragma unroll
            for (int q = 0; q < 8; ++q) idx[q] = s_idx[j + q];
            uint4 u[8];
            #pragma unroll
            for (int q = 0; q < 8; ++q) u[q] = h16[(size_t)idx[q] * 16 + l16];
            #pragma unroll
            for (int q = 0; q < 8; ++q) {
                a0 += bflo(u[q].x); a1 += bfhi(u[q].x);
                a2 += bflo(u[q].y); a3 += bfhi(u[q].y);
                a4 += bflo(u[q].z); a5 += bfhi(u[q].z);
                a6 += bflo(u[q].w); a7 += bfhi(u[q].w);
            }
            j += 8;
        }
        if (j < je) {                        // one predicated tail batch
            #pragma unroll
            for (int q = 0; q < 8; ++q) {
                int ii = j + q;
                int ic = (ii < je - 1) ? ii : (je - 1);
                float sc = (ii < je) ? 1.f : 0.f;
                uint4 u = h16[(size_t)s_idx[ic] * 16 + l16];
                a0 = fmaf(bflo(u.x), sc, a0); a1 = fmaf(bfhi(u.x), sc, a1);
                a2 = fmaf(bflo(u.y), sc, a2); a3 = fmaf(bfhi(u.y), sc, a3);
                a4 = fmaf(bflo(u.z), sc, a4); a5 = fmaf(bfhi(u.z), sc, a5);
                a6 = fmaf(bflo(u.w), sc, a6); a7 = fmaf(bfhi(u.w), sc, a7);
            }
        }
    } else {
        // pathological span (never expected for this input): global indices
        for (int j = jb; j < je; j += 8) {
            #pragma unroll
            for (int q = 0; q < 8; ++q) {
                int ii = j + q;
                int ic = (ii < je - 1) ? ii : (je - 1);
                float sc = (ii < je) ? 1.f : 0.f;
                uint4 u = h16[(size_t)csr16[base + ic] * 16 + l16];
                a0 = fmaf(bflo(u.x), sc, a0); a1 = fmaf(bfhi(u.x), sc, a1);
                a2 = fmaf(bflo(u.y), sc, a2); a3 = fmaf(bfhi(u.y), sc, a3);
                a4 = fmaf(bflo(u.z), sc, a4); a5 = fmaf(bfhi(u.z), sc, a5);
                a6 = fmaf(bflo(u.w), sc, a6); a7 = fmaf(bfhi(u.w), sc, a7);
            }
        }
    }

    {
        uint4 o;
        o.x = (unsigned)f2bf(a0) | ((unsigned)f2bf(a1) << 16);
        o.y = (unsigned)f2bf(a2) | ((unsigned)f2bf(a3) << 16);
        o.z = (unsigned)f2bf(a4) | ((unsigned)f2bf(a5) << 16);
        o.w = (unsigned)f2bf(a6) | ((unsigned)f2bf(a7) << 16);
        *(uint4*)&tile[lr][l16 * 8] = o;
    }
    __syncthreads();

    // ---- Phase 2: MFMA GEMM, wave owns a 32-col slice ----
    f32x4 acc[2];
    acc[0] = (f32x4){0.f, 0.f, 0.f, 0.f};
    acc[1] = (f32x4){0.f, 0.f, 0.f, 0.f};

    #pragma unroll
    for (int kk = 0; kk < 8; ++kk) {
        const unsigned short* Bs = (kk < 4) ? Wrel : Wroot;
        const int kc = (kk & 3) * 32 + quad * 8;
        bf16x8 a;
        if (kk < 4) a = *(const bf16x8*)&tile[mrow][kc];
        else        a = rootv[kk - 4];
        #pragma unroll
        for (int n = 0; n < 2; ++n) {
            const int col0 = (wv * 2 + n) * 16;
            bf16x8 b = *(const bf16x8*)(Bs + (size_t)(col0 + mrow) * 128 + kc);
            acc[n] = __builtin_amdgcn_mfma_f32_16x16x32_bf16(a, b, acc[n], 0, 0, 0);
        }
    }

    __syncthreads();   // RACE FIX: all agg A-frag reads complete before h overwrites tile

    #pragma unroll
    for (int n = 0; n < 2; ++n) {
        const int col = (wv * 2 + n) * 16 + mrow;
        const float bias = b2f(brel[col]);
        #pragma unroll
        for (int i = 0; i < 4; ++i) {
            const int lrow = quad * 4 + i;
            float v = fmaxf(acc[n][i] + bias, 0.f);
            tile[lrow][col] = f2bf(v);
        }
    }
    __syncthreads();   // tile now holds h for the whole 16-row block

    // ---- Phase 3a: coalesced writeback, NON-TEMPORAL (don't pollute L2) ----
    const int isF32 = flags[0];
    {
        const int lr2 = tid >> 4;
        const int c16 = tid & 15;
        u32x4 v = *(const u32x4*)&tile[lr2][c16 * 8];
        __builtin_nontemporal_store(v, (u32x4*)outb + (size_t)(m0 + lr2) * 16 + c16);
        if (outG) {
            if (isF32) {
                f32x4* p = (f32x4*)outG + 160 + (size_t)(m0 + lr2) * 32 + c16 * 2;
                f32x4 f0 = (f32x4){bflo(v.x), bfhi(v.x), bflo(v.y), bfhi(v.y)};
                f32x4 f1 = (f32x4){bflo(v.z), bfhi(v.z), bflo(v.w), bfhi(v.w)};
                __builtin_nontemporal_store(f0, p);
                __builtin_nontemporal_store(f1, p + 1);
            } else {
                u32x4* p = (u32x4*)((unsigned short*)outG + 640);
                __builtin_nontemporal_store(v, p + (size_t)(m0 + lr2) * 16 + c16);
            }
        }
    }

    // ---- Phase 3b: pool; dense partial for first-graph run, atomics only
    //      for boundary-crossing runs ----
    if (tid < 128) {
        const int col = tid;
        const int slice = blockIdx.x & 7;
        int rr = 0;
        float mx = 0.f, sm = 0.f;
        if (ppart) {
            const int g0 = sbatch[0];
            for (; rr < 16 && sbatch[rr] == g0; ++rr) {
                float v = b2f(tile[rr][col]);
                mx = fmaxf(mx, v); sm += v;
            }
            ppart[(size_t)blockIdx.x * 128 + col] =
                (unsigned)f2bf(mx) | ((unsigned)f2bf(sm) << 16);
            mx = 0.f; sm = 0.f;
        }
        if (rr < 16) {
            int curg = sbatch[rr];
            for (; rr < 16; ++rr) {
                int g = sbatch[rr];
                if (g != curg) {
                    atomicMax(&pmx[(slice * GG + curg) * 128 + col], __float_as_uint(mx));
                    unsafeAtomicAdd(&psum[(slice * GG + curg) * 128 + col], sm);
                    curg = g; mx = 0.f; sm = 0.f;
                }
                float v = b2f(tile[rr][col]);
                mx = fmaxf(mx, v);
                sm += v;
            }
            atomicMax(&pmx[(slice * GG + curg) * 128 + col], __float_as_uint(mx));
            unsafeAtomicAdd(&psum[(slice * GG + curg) * 128 + col], sm);
        }
    }
}

// -------------------------------------------------------------------------
// MLP head: ge = atomic slices (boundary runs) + dense per-block partials
// (packed bf16 {mx,sm}) over each graph's block range; gstart table.
// -------------------------------------------------------------------------
__global__ __launch_bounds__(256) void mlp_kernel(const unsigned* __restrict__ pmxL,
                                                  const float* __restrict__ psum,
                                                  const unsigned* __restrict__ part, // [3][3125][128] u32 or null
                                                  const int* __restrict__ gstart,
                                                  const unsigned short* __restrict__ W1,
                                                  const unsigned short* __restrict__ b1,
                                                  const unsigned short* __restrict__ W2,
                                                  const unsigned short* __restrict__ b2,
                                                  const unsigned short* __restrict__ W3,
                                                  const unsigned short* __restrict__ b3,
                                                  void* __restrict__ out,
                                                  const int* __restrict__ flags) {
    int g = blockIdx.x;
    int t = threadIdx.x;
    int isF32 = flags[0];
    __shared__ float sge[256];
    __shared__ float sz1[128];
    __shared__ float sz2[64];

    int start = gstart[g];
    int end   = gstart[g + 1];
    int cnt   = end - start;

    int b_lo = (start + 15) >> 4;
    int b_hi = (cnt > 0) ? ((end - 1) >> 4) : (b_lo - 1);

    float v;
    if (t < 128) {
        v = 0.f;
        #pragma unroll
        for (int L = 0; L < 3; ++L) {
            float m = 0.f;
            #pragma unroll
            for (int s = 0; s < 8; ++s)
                m = fmaxf(m, __uint_as_float(pmxL[((L * 8 + s) * GG + g) * 128 + t]));
            if (part) {
                const unsigned* pm = part + (size_t)L * PARTN * 128;
                for (int b = b_lo; b <= b_hi; ++b)
                    m = fmaxf(m, b2f((unsigned short)(pm[(size_t)b * 128 + t] & 0xffffu)));
            }
            v += m;
        }
    } else {
        float sm = 0.f;
        #pragma unroll
        for (int s = 0; s < 8; ++s) sm += psum[(s * GG + g) * 128 + (t - 128)];
        if (part) {
            #pragma unroll
            for (int L = 0; L < 3; ++L) {
                const unsigned* pm = part + (size_t)L * PARTN * 128;
                for (int b = b_lo; b <= b_hi; ++b)
                    sm += b2f((unsigned short)(pm[(size_t)b * 128 + (t - 128)] >> 16));
            }
        }
        v = sm / fmaxf((float)cnt, 1.f);
    }
    sge[t] = v;
    size_t geo = (size_t)640 + (size_t)NN * 128 + (size_t)g * 256 + t;
    if (isF32) ((float*)out)[geo] = v;
    else       ((unsigned short*)out)[geo] = f2bf(v);
    __syncthreads();

    if (t < 128) {
        float acc = b2f(b1[t]);
        for (int k = 0; k < 256; ++k) acc = fmaf(sge[k], b2f(W1[t * 256 + k]), acc);
        sz1[t] = fmaxf(acc, 0.f);
    }
    __syncthreads();
    if (t < 64) {
        float acc = b2f(b2[t]);
        for (int k = 0; k < 128; ++k) acc = fmaf(sz1[k], b2f(W2[t * 128 + k]), acc);
        sz2[t] = fmaxf(acc, 0.f);
    }
    __syncthreads();
    if (t < 10) {
        float acc = b2f(b3[t]);
        for (int k = 0; k < 64; ++k) acc = fmaf(sz2[k], b2f(W3[t * 64 + k]), acc);
        size_t o = (size_t)g * 10 + t;
        if (isF32) ((float*)out)[o] = acc;
        else       ((unsigned short*)out)[o] = f2bf(acc);
    }
}

// ---- bf16 arena element offsets ----
#define XBF_OFF   0            // x, then h3
#define HA_OFF    6400000      // h1
#define HB_OFF    12800000     // h2
#define WR1_OFF   19200000
#define WO1_OFF   19216384
#define BR1_OFF   19232768
#define WR2_OFF   19232896
#define WO2_OFF   19249280
#define BR2_OFF   19265664
#define WR3_OFF   19265792
#define WO3_OFF   19282176
#define BR3_OFF   19298560
#define W1_OFF    19298688
#define B1_OFF    19331456
#define W2_OFF    19331584
#define B2_OFF    19339776
#define W3_OFF    19339840
#define B3_OFF    19340480
#define ARENA_END 19340490

extern "C" void kernel_launch(void* const* d_in, const int* in_sizes, int n_in,
                              void* d_out, int out_size, void* d_ws, size_t ws_size,
                              hipStream_t stream) {
    unsigned short* arena = (unsigned short*)d_ws;
    size_t intBase = ((size_t)ARENA_END * 2 + 255) & ~(size_t)255;
    char* ib = (char*)d_ws + intBase;
    // int-region layout v7: part OVERLAPS the packed/counts/offsets/bbase
    // region (dead after bucket_sort; conv writes part strictly later in
    // stream order). Total footprint 7.65 MB < r1's proven-fit 7.91 MB,
    // so the dense-pool path is guaranteed active.
    int*            row_ptr = (int*)ib;                        //   200,064 B
    unsigned short* csr_src = (unsigned short*)(ib + 200064);  // 1,600,000 B
    unsigned*       packed  = (unsigned*)(ib + 1800064);       // 3,200,000 B  (dead after sort)
    int*            counts  = (int*)(ib + 5000064);            //   128,000 B  (dead after offsets)
    int*            offsets = (int*)(ib + 5128064);            //   128,000 B  (dead after scatter)
    int*            bbase   = (int*)(ib + 5256064);            //     1,028 B  (dead after sort)
    unsigned*       part    = (unsigned*)(ib + 1800064);       // 4,800,000 B  [3][3125][128] u32 (reuses packed..bbase)
    unsigned*       pmxL    = (unsigned*)(ib + 6600064);       //   786,432 B  [3][8][64][128]
    float*          psum    = (float*)(ib + 7386496);          //   262,144 B  [8][64][128]
    int*            flags   = (int*)(ib + 7648640);            //         8 B (pad to 7,648,768)
    int*            gstart  = (int*)(ib + 7648768);            //       260 B (end 7,649,028)

    size_t need = intBase + 7649028;                           // ~46.33 MB (< r1-proven 46.59)
    unsigned* partP = (ws_size >= need) ? part : nullptr;

    const unsigned* eiw = (const unsigned*)d_in[1];
    const unsigned* bw  = (const unsigned*)d_in[2];
    dim3 blk(256);

    detect_kernel<<<1, 256, 0, stream>>>((const unsigned*)d_in[0], eiw, flags, gstart);

    // Mega prep: convert x + weights + bucket_count + zero pool + gstart.
    WPtrs wp;
    for (int i = 0; i < 15; ++i) wp.p[i] = d_in[3 + i];
    prep_kernel<<<4251, blk, 0, stream>>>(d_in[0], eiw, bw, wp, arena, counts,
                                          (uint4*)pmxL, gstart, flags);

    // CSR build
    bucket_offsets<<<1, blk, 0, stream>>>(counts, offsets, bbase);
    bucket_scatter<<<ABLOCKS, blk, 0, stream>>>(eiw, offsets, packed, flags);
    bucket_sort<<<NBUCK, blk, 0, stream>>>(packed, bbase, csr_src, row_ptr);

    const int convGrid = NN / 16;             // 3125

    // ---- Layer 1: x(X) -> h1(HA) ----  (part plane 0 overwrites dead packed)
    conv_fused<<<convGrid, blk, 0, stream>>>(arena + XBF_OFF, row_ptr, csr_src,
                                             arena + WR1_OFF, arena + WO1_OFF, arena + BR1_OFF,
                                             bw, pmxL, psum,
                                             partP,
                                             arena + HA_OFF, nullptr, flags);
    // ---- Layer 2: h1(HA) -> h2(HB) ----
    conv_fused<<<convGrid, blk, 0, stream>>>(arena + HA_OFF, row_ptr, csr_src,
                                             arena + WR2_OFF, arena + WO2_OFF, arena + BR2_OFF,
                                             bw, pmxL + 65536, psum,
                                             partP ? partP + (size_t)PARTN * 128 : nullptr,
                                             arena + HB_OFF, nullptr, flags);
    // ---- Layer 3: h2(HB) -> h3(X slot) + node_embs to d_out ----
    conv_fused<<<convGrid, blk, 0, stream>>>(arena + HB_OFF, row_ptr, csr_src,
                                             arena + WR3_OFF, arena + WO3_OFF, arena + BR3_OFF,
                                             bw, pmxL + 131072, psum,
                                             partP ? partP + (size_t)2 * PARTN * 128 : nullptr,
                                             arena + XBF_OFF, d_out, flags);

    mlp_kernel<<<GG, blk, 0, stream>>>(pmxL, psum, partP, gstart,
                                       arena + W1_OFF, arena + B1_OFF,
                                       arena + W2_OFF, arena + B2_OFF,
                                       arena + W3_OFF, arena + B3_OFF, d_out, flags);
}

// Round 8
// 337.793 us; speedup vs baseline: 1.2002x; 1.0280x over previous
//
#include <hip/hip_runtime.h>
#include <hip/hip_bf16.h>

#define NN 50000
#define EE 800000
#define GG 64
#define NBUCK 196              // ceil(NN/256)
#define ABLOCKS 125            // edge chunks: 125 x 6400 = 800000
#define CHUNK 6400
#define BCAP 8192              // LDS bucket capacity (mean 4096, sd ~64)
#define SPANCAP 512            // per-block (16-row) staged CSR index cap; mean 256, sd 16
#define PARTN 3125             // conv grid blocks (NN/16)

typedef __attribute__((ext_vector_type(8))) short bf16x8;
typedef __attribute__((ext_vector_type(4))) float f32x4;
typedef __attribute__((ext_vector_type(4))) unsigned int u32x4;

// ---- bf16 helpers ----
__device__ __forceinline__ float bflo(unsigned u) { return __uint_as_float(u << 16); }
__device__ __forceinline__ float bfhi(unsigned u) { return __uint_as_float(u & 0xffff0000u); }
__device__ __forceinline__ float b2f(unsigned short s) { return __uint_as_float(((unsigned)s) << 16); }
__device__ __forceinline__ unsigned short f2bf(float f) {
    __hip_bfloat16 h = __float2bfloat16(f);
    union { __hip_bfloat16 h; unsigned short u; } cv; cv.h = h; return cv.u;
}

// -------------------------------------------------------------------------
// init: zero ghist + gcur (512 ints). Runs before prep (stream order).
// -------------------------------------------------------------------------
__global__ void init_kernel(int* __restrict__ ghist, int* __restrict__ gcur) {
    ghist[threadIdx.x] = 0;
    gcur[threadIdx.x] = 0;
}

// -------------------------------------------------------------------------
// Detector — FALLBACK ONLY (when in_sizes is ambiguous). flags[0]=fp32?
// flags[1]=int64?
// -------------------------------------------------------------------------
__global__ void detect_kernel(const unsigned* __restrict__ xw,
                              const unsigned* __restrict__ eiw,
                              int* __restrict__ flags) {
    __shared__ int s_cnt, s_nz;
    if (threadIdx.x == 0) { s_cnt = 0; s_nz = 0; }
    __syncthreads();
    int cnt = 0;
    for (int i = threadIdx.x; i < 4096; i += 256) {
        unsigned w = xw[(size_t)i * 711];
        unsigned elo = (w >> 7) & 0xFF;
        if (elo >= 100 && elo <= 140) cnt++;
    }
    int nz = 0;
    for (int i = threadIdx.x; i < 1024; i += 256) {
        unsigned w = eiw[(size_t)i * 1560 + 1];
        if (w != 0) nz++;
    }
    atomicAdd(&s_cnt, cnt);
    atomicAdd(&s_nz, nz);
    __syncthreads();
    if (threadIdx.x == 0) {
        flags[0] = (s_cnt < 3600) ? 1 : 0;
        flags[1] = (s_nz  < 8)    ? 1 : 0;
    }
}

// -------------------------------------------------------------------------
// Mega prep: [0,3125) convert x (skipped when host knows input is bf16);
// [3125,3674) convert weights; [3674,3799) bucket_count -> counts + global
// ghist (atomic); [3799,3995) parallel gstart boundary scan;
// [3995,4251) zero pool accumulators (pmxL+psum, 1 MiB exactly).
// -------------------------------------------------------------------------
struct WPtrs { const void* p[15]; };

__global__ __launch_bounds__(256) void prep_kernel(const void* __restrict__ xsrc,
                                                   const unsigned* __restrict__ eiw,
                                                   const unsigned* __restrict__ bw,
                                                   WPtrs wp,
                                                   unsigned short* __restrict__ arena,
                                                   int* __restrict__ counts,
                                                   int* __restrict__ ghist,
                                                   int* __restrict__ gstart,
                                                   uint4* __restrict__ zero_region,
                                                   int hf32, int hi64,
                                                   const int* __restrict__ flags) {
    const int b = blockIdx.x;
    const int tid = threadIdx.x;

    if (b < 3125) {
        if (hf32 == 0) return;             // host knows bf16: conv L1 reads d_in[0]
        const int isF32 = (hf32 > 0) ? 1 : flags[0];
        const int total4 = NN * 128 / 4;   // 1,600,000
        for (int i = b * 256 + tid; i < total4; i += 800000) {
            uint2 o;
            if (isF32) {
                float4 f = ((const float4*)xsrc)[i];
                o.x = (unsigned)f2bf(f.x) | ((unsigned)f2bf(f.y) << 16);
                o.y = (unsigned)f2bf(f.z) | ((unsigned)f2bf(f.w) << 16);
            } else {
                o = ((const uint2*)xsrc)[i];
            }
            ((uint2*)arena)[i] = o;
        }
    } else if (b < 3674) {
        const int isF32 = (hf32 >= 0) ? hf32 : flags[0];
        const int cnt[15] = {16384,128,16384, 16384,128,16384, 16384,128,16384,
                             32768,128,8192,64,640,10};
        const int dst[15] = {19200000,19232768,19216384, 19232896,19265664,19249280,
                             19265792,19298560,19282176,
                             19298688,19331456,19331584,19339776,19339840,19340480};
        const int total = 140490;
        int i = (b - 3125) * 256 + tid;
        if (i < total) {
            int seg = 0, base = 0;
            while (i - base >= cnt[seg]) { base += cnt[seg]; ++seg; }
            int off = i - base;
            const void* s = wp.p[seg];
            arena[dst[seg] + off] =
                isF32 ? f2bf(((const float*)s)[off]) : ((const unsigned short*)s)[off];
        }
    } else if (b < 3799) {
        __shared__ int hist[256];
        hist[tid] = 0;
        __syncthreads();
        const int i64 = (hi64 >= 0) ? hi64 : flags[1];
        const int e0 = (b - 3674) * CHUNK;
        for (int it = 0; it < CHUNK / 256; ++it) {
            int e = e0 + it * 256 + tid;
            int d = (int)(i64 ? eiw[(size_t)2 * (EE + e)] : eiw[EE + e]);
            atomicAdd(&hist[d >> 8], 1);
        }
        __syncthreads();
        counts[(b - 3674) * 256 + tid] = hist[tid];
        atomicAdd(&ghist[tid], hist[tid]);
    } else if (b < 3995) {
        // parallel gstart: one thread per node; boundary writers + tail writer
        const int i64 = (hi64 >= 0) ? hi64 : flags[1];
        int i = (b - 3799) * 256 + tid;
        if (i < NN) {
            int g  = (int)(i64 ? bw[(size_t)2 * i] : bw[i]);
            int gp = (i == 0) ? -1 : (int)(i64 ? bw[(size_t)2 * (i - 1)] : bw[i - 1]);
            for (int gg = gp + 1; gg <= g; ++gg) gstart[gg] = i;   // unique writer
            if (i == NN - 1)
                for (int gg = g + 1; gg <= GG; ++gg) gstart[gg] = NN;
        }
    } else {
        // zero pool accumulators: 256 blocks x 256 thr x 16 B = 1,048,576 B
        zero_region[(b - 3995) * 256 + tid] = (uint4){0, 0, 0, 0};
    }
}

// -------------------------------------------------------------------------
// bucket_scatter: per-block LDS prefix of ghist (bucket bases) + dynamic
// range reservation via one global atomicAdd per (chunk,bucket). Replaces
// the serial single-block bucket_offsets kernel entirely.
// -------------------------------------------------------------------------
__global__ __launch_bounds__(256) void bucket_scatter(const unsigned* __restrict__ eiw,
                                                      const int* __restrict__ counts,
                                                      const int* __restrict__ ghist,
                                                      int* __restrict__ gcur,
                                                      unsigned* __restrict__ packed,
                                                      int hi64,
                                                      const int* __restrict__ flags) {
    __shared__ int stmp[256];
    __shared__ int cur[256];
    const int t = threadIdx.x;
    int gv = ghist[t];
    stmp[t] = gv;
    __syncthreads();
    for (int d = 1; d < 256; d <<= 1) {
        int x = (t >= d) ? stmp[t - d] : 0;
        __syncthreads();
        stmp[t] += x;
        __syncthreads();
    }
    int cnt = counts[blockIdx.x * 256 + t];
    int rel = atomicAdd(&gcur[t], cnt);
    cur[t] = (stmp[t] - gv) + rel;     // bucket_base + reserved offset
    __syncthreads();

    const int i64 = (hi64 >= 0) ? hi64 : flags[1];
    int e0 = blockIdx.x * CHUNK;
    for (int it = 0; it < CHUNK / 256; ++it) {
        int e = e0 + it * 256 + t;
        int s = (int)(i64 ? eiw[(size_t)2 * e]        : eiw[e]);
        int d = (int)(i64 ? eiw[(size_t)2 * (EE + e)] : eiw[EE + e]);
        int pos = atomicAdd(&cur[d >> 8], 1);
        packed[pos] = ((unsigned)s << 8) | (unsigned)(d & 255);
    }
}

__global__ __launch_bounds__(256) void bucket_sort(const unsigned* __restrict__ packed,
                                                   const int* __restrict__ ghist,
                                                   unsigned short* __restrict__ csr_src,
                                                   int* __restrict__ row_ptr) {
    __shared__ unsigned sbuf[BCAP];
    __shared__ int hist[256];
    __shared__ int cur[256];
    __shared__ int sg[256];
    __shared__ int s[256];
    const int t = threadIdx.x;
    const int b = blockIdx.x;

    int gv = ghist[t];
    sg[t] = gv;
    __syncthreads();
    for (int d = 1; d < 256; d <<= 1) {
        int x = (t >= d) ? sg[t - d] : 0;
        __syncthreads();
        sg[t] += x;
        __syncthreads();
    }
    const int nb = ghist[b];           // broadcast load
    const int lo = sg[b] - nb;         // exclusive prefix = bucket base
    int n = (nb > BCAP) ? BCAP : nb;

    hist[t] = 0;
    __syncthreads();
    for (int i = t; i < n; i += 256) {
        unsigned p = packed[lo + i];
        sbuf[i] = p;
        atomicAdd(&hist[p & 255], 1);
    }
    __syncthreads();
    int v = hist[t];
    s[t] = v;
    __syncthreads();
    for (int d = 1; d < 256; d <<= 1) {
        int x = (t >= d) ? s[t - d] : 0;
        __syncthreads();
        s[t] += x;
        __syncthreads();
    }
    int start = s[t] - v;
    int node = b * 256 + t;
    if (node < NN) row_ptr[node] = lo + start;
    if (b == 0 && t == 0) row_ptr[NN] = EE;
    cur[t] = start;
    __syncthreads();
    for (int i = t; i < n; i += 256) {
        unsigned p = sbuf[i];
        int pos = atomicAdd(&cur[p & 255], 1);
        csr_src[lo + pos] = (unsigned short)(p >> 8);
    }
}

// -------------------------------------------------------------------------
// Fused conv v8 = v7b with (a) scalar dtype flags, (b) outb back to normal
// stores (h IS re-read by the next layer — r6 showed NT cost +9.3 MB WRITE
// for no time win), NT kept for outG only (true streaming output).
// -------------------------------------------------------------------------
__global__ __launch_bounds__(256, 4) void conv_fused(const unsigned short* __restrict__ hin,
                                                     const int* __restrict__ row_ptr,
                                                     const unsigned short* __restrict__ csr16,
                                                     const unsigned short* __restrict__ Wrel,
                                                     const unsigned short* __restrict__ Wroot,
                                                     const unsigned short* __restrict__ brel,
                                                     const unsigned* __restrict__ bw,
                                                     unsigned* __restrict__ pmx,   // layer's [8][64][128]
                                                     float* __restrict__ psum,     // [8][64][128] (shared)
                                                     unsigned* __restrict__ ppart, // layer's [3125][128] u32 or null
                                                     unsigned short* __restrict__ outb,
                                                     void* __restrict__ outG,
                                                     int hf32, int hi64,
                                                     const int* __restrict__ flags) {
    __shared__ __align__(16) unsigned short tile[16][136];   // 4.25 KB
    __shared__ int sbatch[16];
    __shared__ int s_rp[17];
    __shared__ unsigned short s_idx[SPANCAP];                // 1 KB

    const int tid  = threadIdx.x;
    const int wv   = tid >> 6;
    const int lane = tid & 63;
    const int m0   = blockIdx.x * 16;
    const int mrow = lane & 15;
    const int quad = lane >> 4;

    // ---- Phase 0: stage row_ptr + CSR indices; sbatch piggybacks ----
    if (tid < 17) s_rp[tid] = row_ptr[m0 + tid];
    if (tid >= 32 && tid < 48) {
        const int i64 = (hi64 >= 0) ? hi64 : flags[1];
        int rr = m0 + (tid - 32);
        sbatch[tid - 32] = (int)(i64 ? bw[(size_t)2 * rr] : bw[rr]);
    }
    __syncthreads();
    const int base = s_rp[0];
    const int span = s_rp[16] - base;
    const int nst  = (span < SPANCAP) ? span : SPANCAP;
    for (int i = tid; i < nst; i += 256) s_idx[i] = csr16[base + i];

    // ---- root-row A-frag hoist (consumed in phase 2, kk=4..7) ----
    bf16x8 rootv[4];
    #pragma unroll
    for (int k2 = 0; k2 < 4; ++k2)
        rootv[k2] = *(const bf16x8*)(hin + (size_t)(m0 + mrow) * 128 + k2 * 32 + quad * 8);

    __syncthreads();

    // ---- Phase 1: gather, quad-per-row, uint4 per lane, 16-deep ----
    const int qd  = lane >> 4;
    const int l16 = lane & 15;
    const int lr  = wv * 4 + qd;
    const int jb  = s_rp[lr]     - base;
    const int je  = s_rp[lr + 1] - base;
    const uint4* h16 = (const uint4*)hin;   // 16 uint4 per 128-ch row

    float a0 = 0.f, a1 = 0.f, a2 = 0.f, a3 = 0.f,
          a4 = 0.f, a5 = 0.f, a6 = 0.f, a7 = 0.f;

    if (span <= SPANCAP) {
        int j = jb;
        for (; j + 16 <= je; j += 16) {      // 16 loads in flight
            int idx[16];
            #pragma unroll
            for (int q = 0; q < 16; ++q) idx[q] = s_idx[j + q];
            uint4 u[16];
            #pragma unroll
            for (int q = 0; q < 16; ++q) u[q] = h16[(size_t)idx[q] * 16 + l16];
            #pragma unroll
            for (int q = 0; q < 16; ++q) {
                a0 += bflo(u[q].x); a1 += bfhi(u[q].x);
                a2 += bflo(u[q].y); a3 += bfhi(u[q].y);
                a4 += bflo(u[q].z); a5 += bfhi(u[q].z);
                a6 += bflo(u[q].w); a7 += bfhi(u[q].w);
            }
        }
        if (j + 8 <= je) {
            int idx[8];
            #pragma unroll
            for (int q = 0; q < 8; ++q) idx[q] = s_idx[j + q];
            uint4 u[8];
            #pragma unroll
            for (int q = 0; q < 8; ++q) u[q] = h16[(size_t)idx[q] * 16 + l16];
            #pragma unroll
            for (int q = 0; q < 8; ++q) {
                a0 += bflo(u[q].x); a1 += bfhi(u[q].x);
                a2 += bflo(u[q].y); a3 += bfhi(u[q].y);
                a4 += bflo(u[q].z); a5 += bfhi(u[q].z);
                a6 += bflo(u[q].w); a7 += bfhi(u[q].w);
            }
            j += 8;
        }
        if (j < je) {                        // one predicated tail batch
            #pragma unroll
            for (int q = 0; q < 8; ++q) {
                int ii = j + q;
                int ic = (ii < je - 1) ? ii : (je - 1);
                float sc = (ii < je) ? 1.f : 0.f;
                uint4 u = h16[(size_t)s_idx[ic] * 16 + l16];
                a0 = fmaf(bflo(u.x), sc, a0); a1 = fmaf(bfhi(u.x), sc, a1);
                a2 = fmaf(bflo(u.y), sc, a2); a3 = fmaf(bfhi(u.y), sc, a3);
                a4 = fmaf(bflo(u.z), sc, a4); a5 = fmaf(bfhi(u.z), sc, a5);
                a6 = fmaf(bflo(u.w), sc, a6); a7 = fmaf(bfhi(u.w), sc, a7);
            }
        }
    } else {
        for (int j = jb; j < je; j += 8) {
            #pragma unroll
            for (int q = 0; q < 8; ++q) {
                int ii = j + q;
                int ic = (ii < je - 1) ? ii : (je - 1);
                float sc = (ii < je) ? 1.f : 0.f;
                uint4 u = h16[(size_t)csr16[base + ic] * 16 + l16];
                a0 = fmaf(bflo(u.x), sc, a0); a1 = fmaf(bfhi(u.x), sc, a1);
                a2 = fmaf(bflo(u.y), sc, a2); a3 = fmaf(bfhi(u.y), sc, a3);
                a4 = fmaf(bflo(u.z), sc, a4); a5 = fmaf(bfhi(u.z), sc, a5);
                a6 = fmaf(bflo(u.w), sc, a6); a7 = fmaf(bfhi(u.w), sc, a7);
            }
        }
    }

    {
        uint4 o;
        o.x = (unsigned)f2bf(a0) | ((unsigned)f2bf(a1) << 16);
        o.y = (unsigned)f2bf(a2) | ((unsigned)f2bf(a3) << 16);
        o.z = (unsigned)f2bf(a4) | ((unsigned)f2bf(a5) << 16);
        o.w = (unsigned)f2bf(a6) | ((unsigned)f2bf(a7) << 16);
        *(uint4*)&tile[lr][l16 * 8] = o;
    }
    __syncthreads();

    // ---- Phase 2: MFMA GEMM, wave owns a 32-col slice ----
    f32x4 acc[2];
    acc[0] = (f32x4){0.f, 0.f, 0.f, 0.f};
    acc[1] = (f32x4){0.f, 0.f, 0.f, 0.f};

    #pragma unroll
    for (int kk = 0; kk < 8; ++kk) {
        const unsigned short* Bs = (kk < 4) ? Wrel : Wroot;
        const int kc = (kk & 3) * 32 + quad * 8;
        bf16x8 a;
        if (kk < 4) a = *(const bf16x8*)&tile[mrow][kc];
        else        a = rootv[kk - 4];
        #pragma unroll
        for (int n = 0; n < 2; ++n) {
            const int col0 = (wv * 2 + n) * 16;
            bf16x8 b = *(const bf16x8*)(Bs + (size_t)(col0 + mrow) * 128 + kc);
            acc[n] = __builtin_amdgcn_mfma_f32_16x16x32_bf16(a, b, acc[n], 0, 0, 0);
        }
    }

    __syncthreads();   // RACE FIX: all agg A-frag reads complete before h overwrites tile

    #pragma unroll
    for (int n = 0; n < 2; ++n) {
        const int col = (wv * 2 + n) * 16 + mrow;
        const float bias = b2f(brel[col]);
        #pragma unroll
        for (int i = 0; i < 4; ++i) {
            const int lrow = quad * 4 + i;
            float v = fmaxf(acc[n][i] + bias, 0.f);
            tile[lrow][col] = f2bf(v);
        }
    }
    __syncthreads();   // tile now holds h for the whole 16-row block

    // ---- Phase 3a: coalesced writeback; outb normal (re-read next layer),
    //      outG non-temporal (streaming final output) ----
    const int isF32 = (hf32 >= 0) ? hf32 : flags[0];
    {
        const int lr2 = tid >> 4;
        const int c16 = tid & 15;
        u32x4 v = *(const u32x4*)&tile[lr2][c16 * 8];
        *((u32x4*)outb + (size_t)(m0 + lr2) * 16 + c16) = v;
        if (outG) {
            if (isF32) {
                f32x4* p = (f32x4*)outG + 160 + (size_t)(m0 + lr2) * 32 + c16 * 2;
                f32x4 f0 = (f32x4){bflo(v.x), bfhi(v.x), bflo(v.y), bfhi(v.y)};
                f32x4 f1 = (f32x4){bflo(v.z), bfhi(v.z), bflo(v.w), bfhi(v.w)};
                __builtin_nontemporal_store(f0, p);
                __builtin_nontemporal_store(f1, p + 1);
            } else {
                u32x4* p = (u32x4*)((unsigned short*)outG + 640);
                __builtin_nontemporal_store(v, p + (size_t)(m0 + lr2) * 16 + c16);
            }
        }
    }

    // ---- Phase 3b: pool; dense partial for first-graph run, atomics only
    //      for boundary-crossing runs ----
    if (tid < 128) {
        const int col = tid;
        const int slice = blockIdx.x & 7;
        int rr = 0;
        float mx = 0.f, sm = 0.f;
        if (ppart) {
            const int g0 = sbatch[0];
            for (; rr < 16 && sbatch[rr] == g0; ++rr) {
                float v = b2f(tile[rr][col]);
                mx = fmaxf(mx, v); sm += v;
            }
            ppart[(size_t)blockIdx.x * 128 + col] =
                (unsigned)f2bf(mx) | ((unsigned)f2bf(sm) << 16);
            mx = 0.f; sm = 0.f;
        }
        if (rr < 16) {
            int curg = sbatch[rr];
            for (; rr < 16; ++rr) {
                int g = sbatch[rr];
                if (g != curg) {
                    atomicMax(&pmx[(slice * GG + curg) * 128 + col], __float_as_uint(mx));
                    unsafeAtomicAdd(&psum[(slice * GG + curg) * 128 + col], sm);
                    curg = g; mx = 0.f; sm = 0.f;
                }
                float v = b2f(tile[rr][col]);
                mx = fmaxf(mx, v);
                sm += v;
            }
            atomicMax(&pmx[(slice * GG + curg) * 128 + col], __float_as_uint(mx));
            unsafeAtomicAdd(&psum[(slice * GG + curg) * 128 + col], sm);
        }
    }
}

// -------------------------------------------------------------------------
// MLP head: ge = atomic slices (boundary runs) + dense per-block partials
// (packed bf16 {mx,sm}) over each graph's block range; gstart table.
// -------------------------------------------------------------------------
__global__ __launch_bounds__(256) void mlp_kernel(const unsigned* __restrict__ pmxL,
                                                  const float* __restrict__ psum,
                                                  const unsigned* __restrict__ part,
                                                  const int* __restrict__ gstart,
                                                  const unsigned short* __restrict__ W1,
                                                  const unsigned short* __restrict__ b1,
                                                  const unsigned short* __restrict__ W2,
                                                  const unsigned short* __restrict__ b2,
                                                  const unsigned short* __restrict__ W3,
                                                  const unsigned short* __restrict__ b3,
                                                  void* __restrict__ out,
                                                  int hf32,
                                                  const int* __restrict__ flags) {
    int g = blockIdx.x;
    int t = threadIdx.x;
    int isF32 = (hf32 >= 0) ? hf32 : flags[0];
    __shared__ float sge[256];
    __shared__ float sz1[128];
    __shared__ float sz2[64];

    int start = gstart[g];
    int end   = gstart[g + 1];
    int cnt   = end - start;

    int b_lo = (start + 15) >> 4;
    int b_hi = (cnt > 0) ? ((end - 1) >> 4) : (b_lo - 1);

    float v;
    if (t < 128) {
        v = 0.f;
        #pragma unroll
        for (int L = 0; L < 3; ++L) {
            float m = 0.f;
            #pragma unroll
            for (int s = 0; s < 8; ++s)
                m = fmaxf(m, __uint_as_float(pmxL[((L * 8 + s) * GG + g) * 128 + t]));
            if (part) {
                const unsigned* pm = part + (size_t)L * PARTN * 128;
                for (int b = b_lo; b <= b_hi; ++b)
                    m = fmaxf(m, b2f((unsigned short)(pm[(size_t)b * 128 + t] & 0xffffu)));
            }
            v += m;
        }
    } else {
        float sm = 0.f;
        #pragma unroll
        for (int s = 0; s < 8; ++s) sm += psum[(s * GG + g) * 128 + (t - 128)];
        if (part) {
            #pragma unroll
            for (int L = 0; L < 3; ++L) {
                const unsigned* pm = part + (size_t)L * PARTN * 128;
                for (int b = b_lo; b <= b_hi; ++b)
                    sm += b2f((unsigned short)(pm[(size_t)b * 128 + (t - 128)] >> 16));
            }
        }
        v = sm / fmaxf((float)cnt, 1.f);
    }
    sge[t] = v;
    size_t geo = (size_t)640 + (size_t)NN * 128 + (size_t)g * 256 + t;
    if (isF32) ((float*)out)[geo] = v;
    else       ((unsigned short*)out)[geo] = f2bf(v);
    __syncthreads();

    if (t < 128) {
        float acc = b2f(b1[t]);
        for (int k = 0; k < 256; ++k) acc = fmaf(sge[k], b2f(W1[t * 256 + k]), acc);
        sz1[t] = fmaxf(acc, 0.f);
    }
    __syncthreads();
    if (t < 64) {
        float acc = b2f(b2[t]);
        for (int k = 0; k < 128; ++k) acc = fmaf(sz1[k], b2f(W2[t * 128 + k]), acc);
        sz2[t] = fmaxf(acc, 0.f);
    }
    __syncthreads();
    if (t < 10) {
        float acc = b2f(b3[t]);
        for (int k = 0; k < 64; ++k) acc = fmaf(sz2[k], b2f(W3[t * 64 + k]), acc);
        size_t o = (size_t)g * 10 + t;
        if (isF32) ((float*)out)[o] = acc;
        else       ((unsigned short*)out)[o] = f2bf(acc);
    }
}

// ---- bf16 arena element offsets ----
#define XBF_OFF   0            // x (fp32 path), then h3
#define HA_OFF    6400000      // h1
#define HB_OFF    12800000     // h2
#define WR1_OFF   19200000
#define WO1_OFF   19216384
#define BR1_OFF   19232768
#define WR2_OFF   19232896
#define WO2_OFF   19249280
#define BR2_OFF   19265664
#define WR3_OFF   19265792
#define WO3_OFF   19282176
#define BR3_OFF   19298560
#define W1_OFF    19298688
#define B1_OFF    19331456
#define W2_OFF    19331584
#define B2_OFF    19339776
#define W3_OFF    19339840
#define B3_OFF    19340480
#define ARENA_END 19340490

extern "C" void kernel_launch(void* const* d_in, const int* in_sizes, int n_in,
                              void* d_out, int out_size, void* d_ws, size_t ws_size,
                              hipStream_t stream) {
    unsigned short* arena = (unsigned short*)d_ws;
    size_t intBase = ((size_t)ARENA_END * 2 + 255) & ~(size_t)255;
    char* ib = (char*)d_ws + intBase;
    // int-region layout v8: part overlaps dead-after-CSR packed+counts.
    int*            row_ptr = (int*)ib;                        //   200,064 B
    unsigned short* csr_src = (unsigned short*)(ib + 200064);  // 1,600,000 B
    unsigned*       packed  = (unsigned*)(ib + 1800064);       // 3,200,000 B (dead after sort)
    int*            counts  = (int*)(ib + 5000064);            //   128,000 B (dead after scatter)
    unsigned*       part    = (unsigned*)(ib + 1800064);       // 4,800,000 B (reuses packed+counts)
    unsigned*       pmxL    = (unsigned*)(ib + 6600064);       //   786,432 B [3][8][64][128]
    float*          psum    = (float*)(ib + 7386496);          //   262,144 B [8][64][128]
    int*            ghist   = (int*)(ib + 7648640);            //     1,024 B
    int*            gcur    = (int*)(ib + 7649664);            //     1,024 B
    int*            flags   = (int*)(ib + 7650688);            //         8 B (pad 128)
    int*            gstart  = (int*)(ib + 7650816);            //       260 B (end 7,651,076)

    size_t need = intBase + 7651076;                           // ~46.33 MB
    unsigned* partP = (ws_size >= need) ? part : nullptr;

    // ---- host-side dtype detection from byte sizes (fallback: detector) ----
    int hf32 = -1, hi64 = -1;
    if (in_sizes && n_in >= 2) {
        if (in_sizes[0] == 25600000)      hf32 = 1;
        else if (in_sizes[0] == 12800000) hf32 = 0;
        if (in_sizes[1] == 12800000)      hi64 = 1;
        else if (in_sizes[1] == 6400000)  hi64 = 0;
    }

    const unsigned* eiw = (const unsigned*)d_in[1];
    const unsigned* bw  = (const unsigned*)d_in[2];
    dim3 blk(256);

    init_kernel<<<1, 256, 0, stream>>>(ghist, gcur);

    if (hf32 < 0 || hi64 < 0)
        detect_kernel<<<1, 256, 0, stream>>>((const unsigned*)d_in[0], eiw, flags);

    WPtrs wp;
    for (int i = 0; i < 15; ++i) wp.p[i] = d_in[3 + i];
    prep_kernel<<<4251, blk, 0, stream>>>(d_in[0], eiw, bw, wp, arena, counts,
                                          ghist, gstart, (uint4*)pmxL,
                                          hf32, hi64, flags);

    bucket_scatter<<<ABLOCKS, blk, 0, stream>>>(eiw, counts, ghist, gcur, packed,
                                                hi64, flags);
    bucket_sort<<<NBUCK, blk, 0, stream>>>(packed, ghist, csr_src, row_ptr);

    const int convGrid = NN / 16;             // 3125

    // layer-1 input: direct bf16 d_in[0] when host knows, else converted arena
    const unsigned short* hin1 =
        (hf32 == 0) ? (const unsigned short*)d_in[0] : (arena + XBF_OFF);

    conv_fused<<<convGrid, blk, 0, stream>>>(hin1, row_ptr, csr_src,
                                             arena + WR1_OFF, arena + WO1_OFF, arena + BR1_OFF,
                                             bw, pmxL, psum,
                                             partP,
                                             arena + HA_OFF, nullptr, hf32, hi64, flags);
    conv_fused<<<convGrid, blk, 0, stream>>>(arena + HA_OFF, row_ptr, csr_src,
                                             arena + WR2_OFF, arena + WO2_OFF, arena + BR2_OFF,
                                             bw, pmxL + 65536, psum,
                                             partP ? partP + (size_t)PARTN * 128 : nullptr,
                                             arena + HB_OFF, nullptr, hf32, hi64, flags);
    conv_fused<<<convGrid, blk, 0, stream>>>(arena + HB_OFF, row_ptr, csr_src,
                                             arena + WR3_OFF, arena + WO3_OFF, arena + BR3_OFF,
                                             bw, pmxL + 131072, psum,
                                             partP ? partP + (size_t)2 * PARTN * 128 : nullptr,
                                             arena + XBF_OFF, d_out, hf32, hi64, flags);

    mlp_kernel<<<GG, blk, 0, stream>>>(pmxL, psum, partP, gstart,
                                       arena + W1_OFF, arena + B1_OFF,
                                       arena + W2_OFF, arena + B2_OFF,
                                       arena + W3_OFF, arena + B3_OFF, d_out,
                                       hf32, flags);
}